// Round 12
// baseline (263.055 us; speedup 1.0000x reference)
//
#include <hip/hip_runtime.h>
#include <hip/hip_bf16.h>
#include <cstddef>

// Shapes (fixed): B=4, H=W=64, C=256, G=8, K=9.
constexpr int HWP = 64 * 64;
constexpr int CCH = 256;
constexpr int OMC = 216;   // G*3*K
constexpr int KDC = 2304;  // 9*256

typedef __attribute__((ext_vector_type(8))) short bf16x8;
typedef __attribute__((ext_vector_type(4))) float f32x4;

__device__ inline unsigned short f2bf(float x) {
  __hip_bfloat16 h = __float2bfloat16(x);
  return *reinterpret_cast<unsigned short*>(&h);
}
__device__ inline float bf2f(unsigned short u) {
  unsigned int v = ((unsigned int)u) << 16;
  return __uint_as_float(v);
}
// unpack a uint holding two bf16: lo -> a, hi -> b
__device__ inline void bfpair(unsigned int u, float& a, float& b) {
  a = __uint_as_float(u << 16);
  b = __uint_as_float(u & 0xffff0000u);
}
// bilinear blend of 4 bf16-pairs with weights wv -> packed bf16 pair
__device__ inline unsigned int blend1(unsigned int ua, unsigned int ub,
                                      unsigned int uc, unsigned int ud,
                                      float4 wv) {
  float a0, a1, b0, b1, c0, c1, d0, d1;
  bfpair(ua, a0, a1); bfpair(ub, b0, b1);
  bfpair(uc, c0, c1); bfpair(ud, d0, d1);
  float v0 = wv.x * a0 + wv.y * b0 + wv.z * c0 + wv.w * d0;
  float v1 = wv.x * a1 + wv.y * b1 + wv.z * c1 + wv.w * d1;
  return (unsigned int)f2bf(v0) | ((unsigned int)f2bf(v1) << 16);
}

// ---------------------------------------------------------------------------
// prep (tiled transpose, coalesced both sides):
//   w_offT[512 n][512 k] ; w_omT[9][256 n(pad)][512 c] ; w_selT[256 n][256 k];
//   w_dcnT[9][256 f][256 c]   (all bf16)
// ---------------------------------------------------------------------------
__global__ __launch_bounds__(256) void prep_transpose(
    const float* __restrict__ w_off, const float* __restrict__ w_om,
    const float* __restrict__ w_sel, const float* __restrict__ w_dcn,
    unsigned short* __restrict__ w_offT, unsigned short* __restrict__ w_omT,
    unsigned short* __restrict__ w_selT, unsigned short* __restrict__ w_dcnT) {
  __shared__ float tile[32][33];
  int bid = blockIdx.x;
  int t = threadIdx.x;
  const float* src;
  unsigned short* dst;
  int in_rs, out_rs, r0, c0, cmax;
  if (bid < 256) {               // w_off: in[512 k][512 n] -> out[n][k]
    int tr = bid >> 4, tc = bid & 15;
    src = w_off; dst = w_offT; in_rs = 512; out_rs = 512;
    r0 = tr * 32; c0 = tc * 32; cmax = 512;
  } else if (bid < 320) {        // w_sel: in[256 k][256 n] -> out[n][k]
    int b2 = bid - 256;
    int tr = b2 >> 3, tc = b2 & 7;
    src = w_sel; dst = w_selT; in_rs = 256; out_rs = 256;
    r0 = tr * 32; c0 = tc * 32; cmax = 256;
  } else if (bid < 896) {        // w_dcn: 9 x in[256 c][256 f] -> out[tap][f][c]
    int b2 = bid - 320;
    int tap = b2 >> 6; b2 &= 63;
    int tr = b2 >> 3, tc = b2 & 7;
    src = w_dcn + (size_t)tap * 65536; dst = w_dcnT + (size_t)tap * 65536;
    in_rs = 256; out_rs = 256;
    r0 = tr * 32; c0 = tc * 32; cmax = 256;
  } else {                       // w_om: 9 x in[512 c][216 n] -> out[tap][256 n][512 c]
    int b2 = bid - 896;
    int tap = b2 >> 7; b2 &= 127;   // 16 r-tiles x 8 c-tiles
    int tr = b2 >> 3, tc = b2 & 7;
    src = w_om + (size_t)tap * 512 * 216; dst = w_omT + (size_t)tap * 256 * 512;
    in_rs = 216; out_rs = 512;
    r0 = tr * 32; c0 = tc * 32; cmax = 216;
  }
  int row = t >> 3, c4 = (t & 7) * 4;
#pragma unroll
  for (int j = 0; j < 4; ++j) {
    int cc = c0 + c4 + j;
    tile[row][c4 + j] = (cc < cmax) ? src[(size_t)(r0 + row) * in_rs + cc] : 0.f;
  }
  __syncthreads();
  ushort4 v;
  v.x = f2bf(tile[c4 + 0][row]);
  v.y = f2bf(tile[c4 + 1][row]);
  v.z = f2bf(tile[c4 + 2][row]);
  v.w = f2bf(tile[c4 + 3][row]);
  *(ushort4*)&dst[(size_t)(c0 + row) * out_rs + r0 + c4] = v;
}

// ---------------------------------------------------------------------------
// Stage 1a/1b: pooled mean (parallel) + attn matvec + sigmoid
// ---------------------------------------------------------------------------
__global__ __launch_bounds__(256) void pool_partial(
    const float* __restrict__ fine, float* __restrict__ partial) {
  int r = blockIdx.x;  // 0..63
  int b = blockIdx.y;  // 0..3
  int t = threadIdx.x;
  const float* src = fine + ((size_t)b * 4096 + r * 64) * 256 + t;
  float s = 0.f;
#pragma unroll 8
  for (int p = 0; p < 64; ++p) s += src[(size_t)p * 256];
  partial[((size_t)b * 64 + r) * 256 + t] = s;
}

__global__ __launch_bounds__(256) void pool_finish(
    const float* __restrict__ partial, const float* __restrict__ w_att,
    float* __restrict__ scale) {
  __shared__ float pl[256];
  int b = blockIdx.x;
  int t = threadIdx.x;
  const float* pp = partial + (size_t)b * 64 * 256 + t;
  float s = 0.f;
#pragma unroll 8
  for (int r = 0; r < 64; ++r) s += pp[(size_t)r * 256];
  pl[t] = s * (1.0f / 4096.0f);
  __syncthreads();
  float acc = 0.f;
  for (int ci = 0; ci < 256; ++ci) acc += pl[ci] * w_att[ci * 256 + t];
  scale[b * 256 + t] = 1.0f + 1.0f / (1.0f + expf(-acc));
}

// ---------------------------------------------------------------------------
// Stage 2: bilinear upsample 32->64 -> upbf (bf16) + 2*up into alignA hi cols
// ---------------------------------------------------------------------------
__global__ __launch_bounds__(256) void upsample_kernel(
    const float* __restrict__ coarse, unsigned short* __restrict__ upbf,
    unsigned short* __restrict__ alignA) {
  int m = blockIdx.x;  // b*4096 + h*64 + w
  int c = threadIdx.x;
  int b = m >> 12, h = (m >> 6) & 63, w = m & 63;
  float cy = fminf(fmaxf(h * 0.5f - 0.25f, 0.f), 31.f);
  float cx = fminf(fmaxf(w * 0.5f - 0.25f, 0.f), 31.f);
  int y0 = (int)cy, x0 = (int)cx;
  float fy = cy - y0, fx = cx - x0;
  int y1 = min(y0 + 1, 31), x1 = min(x0 + 1, 31);
  const float* base = coarse + (size_t)b * 32 * 32 * CCH;
  float v00 = base[(y0 * 32 + x0) * CCH + c];
  float v01 = base[(y0 * 32 + x1) * CCH + c];
  float v10 = base[(y1 * 32 + x0) * CCH + c];
  float v11 = base[(y1 * 32 + x1) * CCH + c];
  float top = v00 + (v01 - v00) * fx;
  float bot = v10 + (v11 - v10) * fx;
  float v = top + (bot - top) * fy;
  upbf[(size_t)m * CCH + c] = f2bf(v);
  alignA[(size_t)m * 512 + 256 + c] = f2bf(2.f * v);
}

// ---------------------------------------------------------------------------
// Stage 3 (MFMA): fine_cal = (fine*scale) @ w_sel -> fp32 finecal (residual)
//                 + bf16 copy into alignA cols 0..255.  Tile 128x64, BK=64.
// XCD-clustered flat grid (A panel per-XCD L2 locality).
// ---------------------------------------------------------------------------
__global__ __launch_bounds__(256) void gemm_finecal_mfma(
    const float* __restrict__ fine, const float* __restrict__ scale,
    const unsigned short* __restrict__ w_selT,   // [256 n][256 k]
    float* __restrict__ finecal, unsigned short* __restrict__ alignA) {
  __shared__ unsigned short As[128][64];
  __shared__ unsigned short Bs[64][64];
  __shared__ float sc[256];
  int i = blockIdx.x;            // flat 0..511
  int xcd = i & 7, j = i >> 3;   // 16 mblk x 4 nblk per XCD
  int mblk = xcd * 16 + (j & 15);   // 0..127
  int nblk = j >> 4;                // 0..3
  int n0 = nblk * 64;
  int m0 = mblk * 128;
  int t = threadIdx.x;
  int wid = t >> 6, lane = t & 63;
  int lrow = lane & 15, lq = lane >> 4;
  int bb = m0 >> 12;  // 128 | 4096: no batch straddle
  sc[t] = scale[bb * 256 + t];
  f32x4 acc[2][4];
#pragma unroll
  for (int ii = 0; ii < 2; ++ii)
#pragma unroll
    for (int jj = 0; jj < 4; ++jj) acc[ii][jj] = (f32x4){0.f, 0.f, 0.f, 0.f};
  for (int k0 = 0; k0 < 256; k0 += 64) {
    __syncthreads();  // also covers sc[] on first iteration
    for (int u = t; u < 128 * 8; u += 256) {
      int row = u >> 3, ck = u & 7;
      const float* fp = &fine[(size_t)(m0 + row) * 256 + k0 + ck * 8];
      float4 f0 = *(const float4*)fp;
      float4 f1 = *(const float4*)(fp + 4);
      int kb = k0 + ck * 8;
      ushort4 u0 = make_ushort4(f2bf(f0.x * sc[kb]), f2bf(f0.y * sc[kb + 1]),
                                f2bf(f0.z * sc[kb + 2]), f2bf(f0.w * sc[kb + 3]));
      ushort4 u1 = make_ushort4(f2bf(f1.x * sc[kb + 4]), f2bf(f1.y * sc[kb + 5]),
                                f2bf(f1.z * sc[kb + 6]), f2bf(f1.w * sc[kb + 7]));
      int cb = (ck ^ (row & 7)) * 8;
      *(ushort4*)&As[row][cb] = u0;
      *(ushort4*)&As[row][cb + 4] = u1;
    }
    for (int u = t; u < 64 * 8; u += 256) {
      int row = u >> 3, ck = u & 7;
      *(uint4*)&Bs[row][(ck ^ (row & 7)) * 8] =
          *(const uint4*)&w_selT[(size_t)(n0 + row) * 256 + k0 + ck * 8];
    }
    __syncthreads();
#pragma unroll
    for (int kk = 0; kk < 2; ++kk) {
      int cs = ((kk * 4 + lq) ^ (lrow & 7)) * 8;
      bf16x8 a[2], b[4];
#pragma unroll
      for (int mt = 0; mt < 2; ++mt)
        a[mt] = *(const bf16x8*)&As[wid * 32 + mt * 16 + lrow][cs];
#pragma unroll
      for (int nt = 0; nt < 4; ++nt)
        b[nt] = *(const bf16x8*)&Bs[nt * 16 + lrow][cs];
#pragma unroll
      for (int mt = 0; mt < 2; ++mt)
#pragma unroll
        for (int nt = 0; nt < 4; ++nt)
          acc[mt][nt] = __builtin_amdgcn_mfma_f32_16x16x32_bf16(
              a[mt], b[nt], acc[mt][nt], 0, 0, 0);
    }
  }
#pragma unroll
  for (int mt = 0; mt < 2; ++mt)
#pragma unroll
    for (int nt = 0; nt < 4; ++nt)
#pragma unroll
      for (int r = 0; r < 4; ++r) {
        int m = m0 + wid * 32 + mt * 16 + lq * 4 + r;
        int n = n0 + nt * 16 + lrow;
        finecal[(size_t)m * 256 + n] = acc[mt][nt][r];
        alignA[(size_t)m * 512 + n] = f2bf(acc[mt][nt][r]);
      }
}

// ---------------------------------------------------------------------------
// Stage 4 (MFMA): align = alignA @ w_off -> bf16 [16384][512]
// gload_lds issue-early double-buffer + XCD-clustered flat grid.
// ---------------------------------------------------------------------------
__global__ __launch_bounds__(256) void gemm_align_mfma(
    const unsigned short* __restrict__ alignA,
    const unsigned short* __restrict__ w_offT,
    unsigned short* __restrict__ alignBf) {
  __shared__ unsigned short As[2][128][64];     // 32 KB
  __shared__ unsigned short Bs[2][64][64];      // 16 KB
  int i = blockIdx.x;            // flat 0..1023
  int xcd = i & 7, j = i >> 3;   // 16 mblk x 8 nblk per XCD
  int mblk = xcd * 16 + (j & 15);   // 0..127
  int nblk = j >> 4;                // 0..7
  int n0 = nblk * 64;
  int m0 = mblk * 128;
  int t = threadIdx.x;
  int wid = t >> 6, lane = t & 63;
  int lrow = lane & 15, lq = lane >> 4;
  f32x4 acc[2][4];
#pragma unroll
  for (int ii = 0; ii < 2; ++ii)
#pragma unroll
    for (int jj = 0; jj < 4; ++jj) acc[ii][jj] = (f32x4){0.f, 0.f, 0.f, 0.f};

  int lr8 = lane >> 3;          // row within 8-row group
  int lslot = lane & 7;         // physical 16B slot
  auto stageA = [&](int buf, int k0) {
#pragma unroll
    for (int ii = 0; ii < 4; ++ii) {
      int rg = wid * 4 + ii;            // 8-row group 0..15
      int row = rg * 8 + lr8;
      int ck = lslot ^ (row & 7);
      const unsigned short* src = &alignA[(size_t)(m0 + row) * 512 + k0 + ck * 8];
      __builtin_amdgcn_global_load_lds(
          (const __attribute__((address_space(1))) unsigned int*)src,
          (__attribute__((address_space(3))) unsigned int*)&As[buf][rg * 8][0],
          16, 0, 0);
    }
  };
  auto stageB = [&](int buf, int k0) {
#pragma unroll
    for (int ii = 0; ii < 2; ++ii) {
      int rg = wid * 2 + ii;            // 8-row group 0..7
      int row = rg * 8 + lr8;
      int ck = lslot ^ (row & 7);
      const unsigned short* src = &w_offT[(size_t)(n0 + row) * 512 + k0 + ck * 8];
      __builtin_amdgcn_global_load_lds(
          (const __attribute__((address_space(1))) unsigned int*)src,
          (__attribute__((address_space(3))) unsigned int*)&Bs[buf][rg * 8][0],
          16, 0, 0);
    }
  };

  stageA(0, 0);
  stageB(0, 0);
  __syncthreads();               // vmcnt(0) drain inserted by compiler
  int buf = 0;
  for (int kb = 0; kb < 8; ++kb) {
    if (kb + 1 < 8) {
      stageA(buf ^ 1, (kb + 1) * 64);  // async, flies under compute
      stageB(buf ^ 1, (kb + 1) * 64);
    }
#pragma unroll
    for (int kk = 0; kk < 2; ++kk) {
      int cs = ((kk * 4 + lq) ^ (lrow & 7)) * 8;
      bf16x8 a[2], b[4];
#pragma unroll
      for (int mt = 0; mt < 2; ++mt)
        a[mt] = *(const bf16x8*)&As[buf][wid * 32 + mt * 16 + lrow][cs];
#pragma unroll
      for (int nt = 0; nt < 4; ++nt)
        b[nt] = *(const bf16x8*)&Bs[buf][nt * 16 + lrow][cs];
#pragma unroll
      for (int mt = 0; mt < 2; ++mt)
#pragma unroll
        for (int nt = 0; nt < 4; ++nt)
          acc[mt][nt] = __builtin_amdgcn_mfma_f32_16x16x32_bf16(
              a[mt], b[nt], acc[mt][nt], 0, 0, 0);
    }
    __syncthreads();             // drains next-tile staging; all reads done
    buf ^= 1;
  }
#pragma unroll
  for (int mt = 0; mt < 2; ++mt)
#pragma unroll
    for (int nt = 0; nt < 4; ++nt)
#pragma unroll
      for (int r = 0; r < 4; ++r) {
        int m = m0 + wid * 32 + mt * 16 + lq * 4 + r;
        int n = n0 + nt * 16 + lrow;
        alignBf[(size_t)m * 512 + n] = f2bf(acc[mt][nt][r]);
      }
}

// ---------------------------------------------------------------------------
// Stage 5 (MFMA): om = conv3x3(align) + b_om  as 9 shifted GEMMs.
// R13 (proven 47 us, conflicts 0): M=256 (4 image rows) x N=64 per block ->
// grid 256 = 1 block/CU, one round. 121.5 KB LDS, 128 B rows (conflict-free).
// ---------------------------------------------------------------------------
__global__ __launch_bounds__(256) void om_conv_mfma(
    const unsigned short* __restrict__ alignBf,  // [16384][512] bf16
    const unsigned short* __restrict__ w_omT,    // [9][256 n][512 c] bf16
    const float* __restrict__ b_om,
    float* __restrict__ om) {                    // [16384][216] fp32
  __shared__ unsigned short As[6][66][64];      // 49.5 KB
  __shared__ unsigned short Bs[9][64][64];      // 72 KB
  int i = blockIdx.x;            // flat 0..255
  int xcd = i & 7, j = i >> 3;   // 32 blocks per XCD, contiguous m-band
  int mblk = xcd * 8 + (j >> 2);    // 0..63 (4 image rows each)
  int nblk = j & 3;                 // 0..3
  int b = mblk >> 4, hq = mblk & 15;
  int h0 = hq * 4;
  int n0 = nblk * 64;
  int t = threadIdx.x;
  int wid = t >> 6, lane = t & 63;  // wave = image row h0+wid
  int lrow = lane & 15, lq = lane >> 4;
  const size_t imgbase = (size_t)b * 4096;
  f32x4 acc[4][4];
#pragma unroll
  for (int ii = 0; ii < 4; ++ii)
#pragma unroll
    for (int jj = 0; jj < 4; ++jj) acc[ii][jj] = (f32x4){0.f, 0.f, 0.f, 0.f};

  int lr8 = lane >> 3;   // sub-index within 8-row/8-px group
  int lslot = lane & 7;  // physical 16B slot

  auto stageB = [&](int c0) {
#pragma unroll
    for (int tap = 0; tap < 9; ++tap) {
#pragma unroll
      for (int ii = 0; ii < 2; ++ii) {
        int rg = wid * 2 + ii;            // 8-row group 0..7
        int row = rg * 8 + lr8;
        int ck = lslot ^ lr8;             // row&7 == lr8
        const unsigned short* src =
            &w_omT[((size_t)tap * 256 + n0 + row) * 512 + c0 * 64 + ck * 8];
        __builtin_amdgcn_global_load_lds(
            (const __attribute__((address_space(1))) unsigned int*)src,
            (__attribute__((address_space(3))) unsigned int*)&Bs[tap][rg * 8][0],
            16, 0, 0);
      }
    }
  };
  auto stageA = [&](int c0) {
#pragma unroll
    for (int dy = 0; dy < 6; ++dy) {
      int y = h0 - 1 + dy;
      if (y < 0 || y > 63) continue;      // OOB row stays pre-zeroed
#pragma unroll
      for (int k = 0; k < 2; ++k) {
        int g = wid * 2 + k;              // 8-px group 0..7
        int px0 = 1 + g * 8;
        int px = px0 + lr8;
        int w = g * 8 + lr8;              // px - 1
        int ck = lslot ^ (px & 7);
        const unsigned short* src =
            &alignBf[(imgbase + (size_t)y * 64 + w) * 512 + c0 * 64 + ck * 8];
        __builtin_amdgcn_global_load_lds(
            (const __attribute__((address_space(1))) unsigned int*)src,
            (__attribute__((address_space(3))) unsigned int*)&As[dy][px0][0],
            16, 0, 0);
      }
    }
  };

  // prologue: zero halo cols (px 0,65) for 6 rows, and fully-OOB dy rows.
  {
    uint4 z = make_uint4(0u, 0u, 0u, 0u);
    if (t < 96) {
      int dy = t >> 4;                    // 0..5
      int px = ((t >> 3) & 1) ? 65 : 0;
      int q = t & 7;
      *(uint4*)&As[dy][px][q * 8] = z;
    }
#pragma unroll
    for (int dy = 0; dy < 6; ++dy) {
      int y = h0 - 1 + dy;
      if (y < 0 || y > 63) {
        unsigned short* rowp = &As[dy][0][0];
        for (int u = t; u < 528; u += 256)  // 66*64 shorts = 528 uint4
          *(uint4*)&rowp[u * 8] = z;
      }
    }
  }
  stageA(0);
  stageB(0);

  for (int c0 = 0; c0 < 8; ++c0) {
    __syncthreads();  // drains staging (vmcnt) + zero writes
#pragma unroll
    for (int tap = 0; tap < 9; ++tap) {
      int dyt = tap / 3, dxt = tap - dyt * 3;
#pragma unroll
      for (int kk = 0; kk < 2; ++kk) {
        bf16x8 a[4], bb[4];
#pragma unroll
        for (int mt = 0; mt < 4; ++mt) {
          int prow = mt * 16 + lrow + dxt;
          a[mt] = *(const bf16x8*)&As[wid + dyt][prow][((kk * 4 + lq) ^ (prow & 7)) * 8];
        }
#pragma unroll
        for (int nt = 0; nt < 4; ++nt)
          bb[nt] = *(const bf16x8*)&Bs[tap][nt * 16 + lrow]
                                      [((kk * 4 + lq) ^ (lrow & 7)) * 8];
#pragma unroll
        for (int mt = 0; mt < 4; ++mt)
#pragma unroll
          for (int nt = 0; nt < 4; ++nt)
            acc[mt][nt] = __builtin_amdgcn_mfma_f32_16x16x32_bf16(
                a[mt], bb[nt], acc[mt][nt], 0, 0, 0);
      }
    }
    __syncthreads();  // all reads done before restage
    if (c0 < 7) {
      stageA(c0 + 1);
      stageB(c0 + 1);
    }
  }
  // epilogue: direct store + bias (n < 216)
#pragma unroll
  for (int nt = 0; nt < 4; ++nt) {
    int n = n0 + nt * 16 + lrow;
    if (n < OMC) {
      float bias = b_om[n];
#pragma unroll
      for (int mt = 0; mt < 4; ++mt) {
#pragma unroll
        for (int r = 0; r < 4; ++r) {
          size_t m = imgbase + (size_t)(h0 + wid) * 64 + mt * 16 + lq * 4 + r;
          om[m * OMC + n] = acc[mt][nt][r] + bias;
        }
      }
    }
  }
}

// ---------------------------------------------------------------------------
// Stage 6 (FUSED): deformable sampling + out = relu(S @ w_dcnT + b_dcn) + finecal
// T14 issue-early/consume-late split, gather state in NAMED registers
// (g0..g7; no runtime-indexed arrays -> no scratch risk). Per kb step:
//   barrier -> sampleLoad (gathers -> g0..g7, in flight) + stageB(gload_lds)
//   -> gemmStep(buf) [vmcnt wait for gathers lands AFTER the cluster]
//   -> [computeOW once per tap] -> sampleStore (blend + swizzled ds_write
//   into As[buf^1]).
// ---------------------------------------------------------------------------
__global__ __launch_bounds__(256) void dcn_fused(
    const float* __restrict__ om, const unsigned short* __restrict__ upbf,
    const unsigned short* __restrict__ w_dcnT,  // [9][256 f][256 c]
    const float* __restrict__ b_dcn,
    const float* __restrict__ finecal,
    float* __restrict__ outp) {
  __shared__ unsigned short As[2][64][64];    // 16 KB
  __shared__ unsigned short Bs[2][256][64];   // 64 KB
  __shared__ int   offs[2][64][8][4];         // 16 KB
  __shared__ float wts[2][64][8][4];          // 16 KB
  int i = blockIdx.x;            // 0..255
  int xcd = i & 7, j = i >> 3;   // contiguous 32-row band per XCD
  int bh = xcd * 32 + j;         // 0..255 (b*64+h)
  int b = bh >> 6, h = bh & 63;
  const size_t m0 = (size_t)bh * 64;
  const unsigned short* upb = upbf + (size_t)b * HWP * CCH;
  int t = threadIdx.x;
  int wid = t >> 6, lane = t & 63;
  int lrow = lane & 15, lq = lane >> 4;
  f32x4 acc[4][4];
#pragma unroll
  for (int ii = 0; ii < 4; ++ii)
#pragma unroll
    for (int jj = 0; jj < 4; ++jj) acc[ii][jj] = (f32x4){0.f, 0.f, 0.f, 0.f};

  int lr8 = lane >> 3;   // row within 8-row group
  int lslot = lane & 7;  // physical 16B slot
  int px_s = t >> 2, tq_s = t & 3;   // sampling decomposition

  // named gather registers (T14 in-flight state)
  uint4 g0, g1, g2, g3, g4, g5, g6, g7;
  float4 wv;

  // per-tap offsets/weights for all 64 px x 8 groups (512 entries, 2/thread)
  auto computeOW = [&](int owb, int tap) {
    int ky = tap / 3, kx = tap - ky * 3;
    for (int e = t; e < 512; e += 256) {
      int p = e >> 3, gg = e & 7;
      const float* omr = om + (m0 + p) * OMC;
      float dy = omr[gg * 18 + tap * 2];
      float dx = omr[gg * 18 + tap * 2 + 1];
      float mk = 1.0f / (1.0f + expf(-omr[144 + gg * 9 + tap]));
      float sy = (float)(h + ky - 1) + dy;
      float sx = (float)(p + kx - 1) + dx;
      float y0f = floorf(sy), x0f = floorf(sx);
      float fy = sy - y0f, fx = sx - x0f;
      int y0 = (int)y0f, x0 = (int)x0f;
      int y1 = y0 + 1, x1 = x0 + 1;
      float vy0 = (y0 >= 0 && y0 <= 63) ? 1.f : 0.f;
      float vy1 = (y1 >= 0 && y1 <= 63) ? 1.f : 0.f;
      float vx0 = (x0 >= 0 && x0 <= 63) ? 1.f : 0.f;
      float vx1 = (x1 >= 0 && x1 <= 63) ? 1.f : 0.f;
      int yc0 = min(max(y0, 0), 63), yc1 = min(max(y1, 0), 63);
      int xc0 = min(max(x0, 0), 63), xc1 = min(max(x1, 0), 63);
      offs[owb][p][gg][0] = (yc0 * 64 + xc0) * 256;
      offs[owb][p][gg][1] = (yc0 * 64 + xc1) * 256;
      offs[owb][p][gg][2] = (yc1 * 64 + xc0) * 256;
      offs[owb][p][gg][3] = (yc1 * 64 + xc1) * 256;
      wts[owb][p][gg][0] = (1.f - fy) * (1.f - fx) * vy0 * vx0 * mk;
      wts[owb][p][gg][1] = (1.f - fy) * fx * vy0 * vx1 * mk;
      wts[owb][p][gg][2] = fy * (1.f - fx) * vy1 * vx0 * mk;
      wts[owb][p][gg][3] = fy * fx * vy1 * vx1 * mk;
    }
  };

  // stage B[256 f][64 c] for kb via global_load_lds (src-side XOR swizzle)
  auto stageB = [&](int buf, int kb) {
    int tap = kb >> 2, c0 = (kb & 3) * 64;
#pragma unroll
    for (int ii = 0; ii < 8; ++ii) {
      int rg = wid * 8 + ii;            // 8-row group 0..31
      int row = rg * 8 + lr8;
      int ck = lslot ^ (row & 7);
      const unsigned short* src =
          &w_dcnT[((size_t)tap * 256 + row) * 256 + c0 + ck * 8];
      __builtin_amdgcn_global_load_lds(
          (const __attribute__((address_space(1))) unsigned int*)src,
          (__attribute__((address_space(3))) unsigned int*)&Bs[buf][rg * 8][0],
          16, 0, 0);
    }
  };

  // T14 part 1: issue the 8 corner gathers into named registers.
  auto sampleLoad = [&](int kb, int owb) {
    int c0q = kb & 3;
    int g = c0q * 2 + (tq_s >> 1);
    int4 o = *(const int4*)&offs[owb][px_s][g][0];
    wv = *(const float4*)&wts[owb][px_s][g][0];
    int c0 = c0q * 64 + tq_s * 16;
    g0 = *(const uint4*)&upb[o.x + c0];
    g1 = *(const uint4*)&upb[o.y + c0];
    g2 = *(const uint4*)&upb[o.z + c0];
    g3 = *(const uint4*)&upb[o.w + c0];
    g4 = *(const uint4*)&upb[o.x + c0 + 8];
    g5 = *(const uint4*)&upb[o.y + c0 + 8];
    g6 = *(const uint4*)&upb[o.z + c0 + 8];
    g7 = *(const uint4*)&upb[o.w + c0 + 8];
  };
  // blend one 8-channel run and write the swizzled 16B chunk.
  auto blendStore = [&](int buf, int hc, uint4 pa, uint4 pb, uint4 pc, uint4 pd) {
    uint4 res;
    res.x = blend1(pa.x, pb.x, pc.x, pd.x, wv);
    res.y = blend1(pa.y, pb.y, pc.y, pd.y, wv);
    res.z = blend1(pa.z, pb.z, pc.z, pd.z, wv);
    res.w = blend1(pa.w, pb.w, pc.w, pd.w, wv);
    int chunk = tq_s * 2 + hc;
    *(uint4*)&As[buf][px_s][(chunk ^ (px_s & 7)) * 8] = res;
  };
  // T14 part 2: blend + swizzled ds_write (runs after the MFMA cluster).
  auto sampleStore = [&](int buf) {
    blendStore(buf, 0, g0, g1, g2, g3);
    blendStore(buf, 1, g4, g5, g6, g7);
  };

  auto gemmStep = [&](int buf) {
#pragma unroll
    for (int kk = 0; kk < 2; ++kk) {
      int cs = ((kk * 4 + lq) ^ (lrow & 7)) * 8;
      bf16x8 a[4], bv[4];
#pragma unroll
      for (int mt = 0; mt < 4; ++mt)
        a[mt] = *(const bf16x8*)&As[buf][mt * 16 + lrow][cs];
#pragma unroll
      for (int nt = 0; nt < 4; ++nt)
        bv[nt] = *(const bf16x8*)&Bs[buf][wid * 64 + nt * 16 + lrow][cs];
#pragma unroll
      for (int mt = 0; mt < 4; ++mt)
#pragma unroll
        for (int nt = 0; nt < 4; ++nt)
          acc[mt][nt] = __builtin_amdgcn_mfma_f32_16x16x32_bf16(
              a[mt], bv[nt], acc[mt][nt], 0, 0, 0);
    }
  };

  // prologue: ow(0), then stage tile 0 (load + immediate store)
  computeOW(0, 0);
  __syncthreads();              // ow(0) visible
  sampleLoad(0, 0);
  stageB(0, 0);
  sampleStore(0);

  int buf = 0;
  for (int kb = 0; kb < 36; ++kb) {
    int tap = kb >> 2, c0q = kb & 3;
    __syncthreads();            // drains sample writes + stage vmcnt; prior
                                // reads of buf^1 finished -> safe to rewrite
    int nkb = kb + 1;
    if (nkb < 36) {
      sampleLoad(nkb, (nkb >> 2) & 1);  // gathers in flight
      stageB(buf ^ 1, nkb);             // async, under compute
    }
    gemmStep(buf);              // MFMA cluster covers gather latency
    if (c0q == 2 && tap < 8) computeOW((tap + 1) & 1, tap + 1);
    if (nkb < 36) sampleStore(buf ^ 1);
    buf ^= 1;
  }

  // epilogue: out = relu(acc + bias) + finecal
#pragma unroll
  for (int mt = 0; mt < 4; ++mt)
#pragma unroll
    for (int nt = 0; nt < 4; ++nt) {
      int f = wid * 64 + nt * 16 + lrow;
      float bias = b_dcn[f];
#pragma unroll
      for (int r = 0; r < 4; ++r) {
        size_t m = m0 + mt * 16 + lq * 4 + r;
        float v = fmaxf(acc[mt][nt][r] + bias, 0.f);
        float fc = __builtin_nontemporal_load(&finecal[m * 256 + f]);
        __builtin_nontemporal_store(v + fc, &outp[m * 256 + f]);
      }
    }
}

// ---------------------------------------------------------------------------
extern "C" void kernel_launch(void* const* d_in, const int* in_sizes, int n_in,
                              void* d_out, int out_size, void* d_ws, size_t ws_size,
                              hipStream_t stream) {
  const float* coarse = (const float*)d_in[0];
  const float* fine   = (const float*)d_in[1];
  const float* w_att  = (const float*)d_in[2];
  const float* w_sel  = (const float*)d_in[3];
  const float* w_off  = (const float*)d_in[4];
  const float* w_om   = (const float*)d_in[5];
  const float* b_om   = (const float*)d_in[6];
  const float* w_dcn  = (const float*)d_in[7];
  const float* b_dcn  = (const float*)d_in[8];
  float* outp = (float*)d_out;

  char* base = (char*)d_ws;
  size_t o = 0;
  float* scale            = (float*)(base + o);          o += 4096;
  float* finecal          = (float*)(base + o);          o += 16777216;
  float* omb              = (float*)(base + o);          o += 14155776;
  unsigned short* upbf    = (unsigned short*)(base + o); o += 8388608;
  unsigned short* w_offT  = (unsigned short*)(base + o); o += 524288;
  unsigned short* w_omT   = (unsigned short*)(base + o); o += 2359296;  // 9*256*512
  unsigned short* w_selT  = (unsigned short*)(base + o); o += 131072;
  unsigned short* w_dcnT  = (unsigned short*)(base + o); o += 1179648;
  unsigned short* scratch = (unsigned short*)(base + o);  // align region
  // alignA/alignBf live in the former S region (dead by dcn time):
  unsigned short* alignA  = scratch;
  unsigned short* alignBf = (unsigned short*)((char*)scratch + 16777216);
  // partial pooling buffer aliases omb (dead until om_conv writes it)
  float* partial = omb;

  prep_transpose<<<dim3(2048), dim3(256), 0, stream>>>(
      w_off, w_om, w_sel, w_dcn, w_offT, w_omT, w_selT, w_dcnT);
  pool_partial<<<dim3(64, 4), dim3(256), 0, stream>>>(fine, partial);
  pool_finish<<<dim3(4), dim3(256), 0, stream>>>(partial, w_att, scale);
  upsample_kernel<<<dim3(16384), dim3(256), 0, stream>>>(coarse, upbf, alignA);
  gemm_finecal_mfma<<<dim3(512), dim3(256), 0, stream>>>(
      fine, scale, w_selT, finecal, alignA);
  gemm_align_mfma<<<dim3(1024), dim3(256), 0, stream>>>(alignA, w_offT, alignBf);
  om_conv_mfma<<<dim3(256), dim3(256), 0, stream>>>(alignBf, w_omT, b_om, omb);
  dcn_fused<<<dim3(256), dim3(256), 0, stream>>>(
      omb, upbf, w_dcnT, b_dcn, finecal, outp);
}

// Round 13
// 240.332 us; speedup vs baseline: 1.0945x; 1.0945x over previous
//
#include <hip/hip_runtime.h>
#include <hip/hip_bf16.h>
#include <cstddef>

// Shapes (fixed): B=4, H=W=64, C=256, G=8, K=9.
constexpr int HWP = 64 * 64;
constexpr int CCH = 256;
constexpr int OMC = 216;   // G*3*K
constexpr int KDC = 2304;  // 9*256

typedef __attribute__((ext_vector_type(8))) short bf16x8;
typedef __attribute__((ext_vector_type(4))) float f32x4;

__device__ inline unsigned short f2bf(float x) {
  __hip_bfloat16 h = __float2bfloat16(x);
  return *reinterpret_cast<unsigned short*>(&h);
}
__device__ inline float bf2f(unsigned short u) {
  unsigned int v = ((unsigned int)u) << 16;
  return __uint_as_float(v);
}
// unpack a uint holding two bf16: lo -> a, hi -> b
__device__ inline void bfpair(unsigned int u, float& a, float& b) {
  a = __uint_as_float(u << 16);
  b = __uint_as_float(u & 0xffff0000u);
}
// bilinear blend of 4 bf16-pairs with weights wv -> packed bf16 pair
__device__ inline unsigned int blend1(unsigned int ua, unsigned int ub,
                                      unsigned int uc, unsigned int ud,
                                      float4 wv) {
  float a0, a1, b0, b1, c0, c1, d0, d1;
  bfpair(ua, a0, a1); bfpair(ub, b0, b1);
  bfpair(uc, c0, c1); bfpair(ud, d0, d1);
  float v0 = wv.x * a0 + wv.y * b0 + wv.z * c0 + wv.w * d0;
  float v1 = wv.x * a1 + wv.y * b1 + wv.z * c1 + wv.w * d1;
  return (unsigned int)f2bf(v0) | ((unsigned int)f2bf(v1) << 16);
}

// ---------------------------------------------------------------------------
// prep (tiled transpose, coalesced both sides):
//   w_offT[512 n][512 k] ; w_omT[9][256 n(pad)][512 c] ; w_selT[256 n][256 k];
//   w_dcnT[9][256 f][256 c]   (all bf16)
// ---------------------------------------------------------------------------
__global__ __launch_bounds__(256) void prep_transpose(
    const float* __restrict__ w_off, const float* __restrict__ w_om,
    const float* __restrict__ w_sel, const float* __restrict__ w_dcn,
    unsigned short* __restrict__ w_offT, unsigned short* __restrict__ w_omT,
    unsigned short* __restrict__ w_selT, unsigned short* __restrict__ w_dcnT) {
  __shared__ float tile[32][33];
  int bid = blockIdx.x;
  int t = threadIdx.x;
  const float* src;
  unsigned short* dst;
  int in_rs, out_rs, r0, c0, cmax;
  if (bid < 256) {               // w_off: in[512 k][512 n] -> out[n][k]
    int tr = bid >> 4, tc = bid & 15;
    src = w_off; dst = w_offT; in_rs = 512; out_rs = 512;
    r0 = tr * 32; c0 = tc * 32; cmax = 512;
  } else if (bid < 320) {        // w_sel: in[256 k][256 n] -> out[n][k]
    int b2 = bid - 256;
    int tr = b2 >> 3, tc = b2 & 7;
    src = w_sel; dst = w_selT; in_rs = 256; out_rs = 256;
    r0 = tr * 32; c0 = tc * 32; cmax = 256;
  } else if (bid < 896) {        // w_dcn: 9 x in[256 c][256 f] -> out[tap][f][c]
    int b2 = bid - 320;
    int tap = b2 >> 6; b2 &= 63;
    int tr = b2 >> 3, tc = b2 & 7;
    src = w_dcn + (size_t)tap * 65536; dst = w_dcnT + (size_t)tap * 65536;
    in_rs = 256; out_rs = 256;
    r0 = tr * 32; c0 = tc * 32; cmax = 256;
  } else {                       // w_om: 9 x in[512 c][216 n] -> out[tap][256 n][512 c]
    int b2 = bid - 896;
    int tap = b2 >> 7; b2 &= 127;   // 16 r-tiles x 8 c-tiles
    int tr = b2 >> 3, tc = b2 & 7;
    src = w_om + (size_t)tap * 512 * 216; dst = w_omT + (size_t)tap * 256 * 512;
    in_rs = 216; out_rs = 512;
    r0 = tr * 32; c0 = tc * 32; cmax = 216;
  }
  int row = t >> 3, c4 = (t & 7) * 4;
#pragma unroll
  for (int j = 0; j < 4; ++j) {
    int cc = c0 + c4 + j;
    tile[row][c4 + j] = (cc < cmax) ? src[(size_t)(r0 + row) * in_rs + cc] : 0.f;
  }
  __syncthreads();
  ushort4 v;
  v.x = f2bf(tile[c4 + 0][row]);
  v.y = f2bf(tile[c4 + 1][row]);
  v.z = f2bf(tile[c4 + 2][row]);
  v.w = f2bf(tile[c4 + 3][row]);
  *(ushort4*)&dst[(size_t)(c0 + row) * out_rs + r0 + c4] = v;
}

// ---------------------------------------------------------------------------
// Stage 1a/1b: pooled mean (parallel) + attn matvec + sigmoid
// ---------------------------------------------------------------------------
__global__ __launch_bounds__(256) void pool_partial(
    const float* __restrict__ fine, float* __restrict__ partial) {
  int r = blockIdx.x;  // 0..63
  int b = blockIdx.y;  // 0..3
  int t = threadIdx.x;
  const float* src = fine + ((size_t)b * 4096 + r * 64) * 256 + t;
  float s = 0.f;
#pragma unroll 8
  for (int p = 0; p < 64; ++p) s += src[(size_t)p * 256];
  partial[((size_t)b * 64 + r) * 256 + t] = s;
}

__global__ __launch_bounds__(256) void pool_finish(
    const float* __restrict__ partial, const float* __restrict__ w_att,
    float* __restrict__ scale) {
  __shared__ float pl[256];
  int b = blockIdx.x;
  int t = threadIdx.x;
  const float* pp = partial + (size_t)b * 64 * 256 + t;
  float s = 0.f;
#pragma unroll 8
  for (int r = 0; r < 64; ++r) s += pp[(size_t)r * 256];
  pl[t] = s * (1.0f / 4096.0f);
  __syncthreads();
  float acc = 0.f;
  for (int ci = 0; ci < 256; ++ci) acc += pl[ci] * w_att[ci * 256 + t];
  scale[b * 256 + t] = 1.0f + 1.0f / (1.0f + expf(-acc));
}

// ---------------------------------------------------------------------------
// Stage 2: bilinear upsample 32->64 -> upbf (bf16) + 2*up into alignA hi cols
// ---------------------------------------------------------------------------
__global__ __launch_bounds__(256) void upsample_kernel(
    const float* __restrict__ coarse, unsigned short* __restrict__ upbf,
    unsigned short* __restrict__ alignA) {
  int m = blockIdx.x;  // b*4096 + h*64 + w
  int c = threadIdx.x;
  int b = m >> 12, h = (m >> 6) & 63, w = m & 63;
  float cy = fminf(fmaxf(h * 0.5f - 0.25f, 0.f), 31.f);
  float cx = fminf(fmaxf(w * 0.5f - 0.25f, 0.f), 31.f);
  int y0 = (int)cy, x0 = (int)cx;
  float fy = cy - y0, fx = cx - x0;
  int y1 = min(y0 + 1, 31), x1 = min(x0 + 1, 31);
  const float* base = coarse + (size_t)b * 32 * 32 * CCH;
  float v00 = base[(y0 * 32 + x0) * CCH + c];
  float v01 = base[(y0 * 32 + x1) * CCH + c];
  float v10 = base[(y1 * 32 + x0) * CCH + c];
  float v11 = base[(y1 * 32 + x1) * CCH + c];
  float top = v00 + (v01 - v00) * fx;
  float bot = v10 + (v11 - v10) * fx;
  float v = top + (bot - top) * fy;
  upbf[(size_t)m * CCH + c] = f2bf(v);
  alignA[(size_t)m * 512 + 256 + c] = f2bf(2.f * v);
}

// ---------------------------------------------------------------------------
// Stage 3 (MFMA): fine_cal = (fine*scale) @ w_sel -> fp32 finecal (residual)
//                 + bf16 copy into alignA cols 0..255.  Tile 128x64, BK=64.
// XCD-clustered flat grid (A panel per-XCD L2 locality).
// ---------------------------------------------------------------------------
__global__ __launch_bounds__(256) void gemm_finecal_mfma(
    const float* __restrict__ fine, const float* __restrict__ scale,
    const unsigned short* __restrict__ w_selT,   // [256 n][256 k]
    float* __restrict__ finecal, unsigned short* __restrict__ alignA) {
  __shared__ unsigned short As[128][64];
  __shared__ unsigned short Bs[64][64];
  __shared__ float sc[256];
  int i = blockIdx.x;            // flat 0..511
  int xcd = i & 7, j = i >> 3;   // 16 mblk x 4 nblk per XCD
  int mblk = xcd * 16 + (j & 15);   // 0..127
  int nblk = j >> 4;                // 0..3
  int n0 = nblk * 64;
  int m0 = mblk * 128;
  int t = threadIdx.x;
  int wid = t >> 6, lane = t & 63;
  int lrow = lane & 15, lq = lane >> 4;
  int bb = m0 >> 12;  // 128 | 4096: no batch straddle
  sc[t] = scale[bb * 256 + t];
  f32x4 acc[2][4];
#pragma unroll
  for (int ii = 0; ii < 2; ++ii)
#pragma unroll
    for (int jj = 0; jj < 4; ++jj) acc[ii][jj] = (f32x4){0.f, 0.f, 0.f, 0.f};
  for (int k0 = 0; k0 < 256; k0 += 64) {
    __syncthreads();  // also covers sc[] on first iteration
    for (int u = t; u < 128 * 8; u += 256) {
      int row = u >> 3, ck = u & 7;
      const float* fp = &fine[(size_t)(m0 + row) * 256 + k0 + ck * 8];
      float4 f0 = *(const float4*)fp;
      float4 f1 = *(const float4*)(fp + 4);
      int kb = k0 + ck * 8;
      ushort4 u0 = make_ushort4(f2bf(f0.x * sc[kb]), f2bf(f0.y * sc[kb + 1]),
                                f2bf(f0.z * sc[kb + 2]), f2bf(f0.w * sc[kb + 3]));
      ushort4 u1 = make_ushort4(f2bf(f1.x * sc[kb + 4]), f2bf(f1.y * sc[kb + 5]),
                                f2bf(f1.z * sc[kb + 6]), f2bf(f1.w * sc[kb + 7]));
      int cb = (ck ^ (row & 7)) * 8;
      *(ushort4*)&As[row][cb] = u0;
      *(ushort4*)&As[row][cb + 4] = u1;
    }
    for (int u = t; u < 64 * 8; u += 256) {
      int row = u >> 3, ck = u & 7;
      *(uint4*)&Bs[row][(ck ^ (row & 7)) * 8] =
          *(const uint4*)&w_selT[(size_t)(n0 + row) * 256 + k0 + ck * 8];
    }
    __syncthreads();
#pragma unroll
    for (int kk = 0; kk < 2; ++kk) {
      int cs = ((kk * 4 + lq) ^ (lrow & 7)) * 8;
      bf16x8 a[2], b[4];
#pragma unroll
      for (int mt = 0; mt < 2; ++mt)
        a[mt] = *(const bf16x8*)&As[wid * 32 + mt * 16 + lrow][cs];
#pragma unroll
      for (int nt = 0; nt < 4; ++nt)
        b[nt] = *(const bf16x8*)&Bs[nt * 16 + lrow][cs];
#pragma unroll
      for (int mt = 0; mt < 2; ++mt)
#pragma unroll
        for (int nt = 0; nt < 4; ++nt)
          acc[mt][nt] = __builtin_amdgcn_mfma_f32_16x16x32_bf16(
              a[mt], b[nt], acc[mt][nt], 0, 0, 0);
    }
  }
#pragma unroll
  for (int mt = 0; mt < 2; ++mt)
#pragma unroll
    for (int nt = 0; nt < 4; ++nt)
#pragma unroll
      for (int r = 0; r < 4; ++r) {
        int m = m0 + wid * 32 + mt * 16 + lq * 4 + r;
        int n = n0 + nt * 16 + lrow;
        finecal[(size_t)m * 256 + n] = acc[mt][nt][r];
        alignA[(size_t)m * 512 + n] = f2bf(acc[mt][nt][r]);
      }
}

// ---------------------------------------------------------------------------
// Stage 4 (MFMA): align = alignA @ w_off -> bf16 [16384][512]
// gload_lds issue-early double-buffer + XCD-clustered flat grid.
// ---------------------------------------------------------------------------
__global__ __launch_bounds__(256) void gemm_align_mfma(
    const unsigned short* __restrict__ alignA,
    const unsigned short* __restrict__ w_offT,
    unsigned short* __restrict__ alignBf) {
  __shared__ unsigned short As[2][128][64];     // 32 KB
  __shared__ unsigned short Bs[2][64][64];      // 16 KB
  int i = blockIdx.x;            // flat 0..1023
  int xcd = i & 7, j = i >> 3;   // 16 mblk x 8 nblk per XCD
  int mblk = xcd * 16 + (j & 15);   // 0..127
  int nblk = j >> 4;                // 0..7
  int n0 = nblk * 64;
  int m0 = mblk * 128;
  int t = threadIdx.x;
  int wid = t >> 6, lane = t & 63;
  int lrow = lane & 15, lq = lane >> 4;
  f32x4 acc[2][4];
#pragma unroll
  for (int ii = 0; ii < 2; ++ii)
#pragma unroll
    for (int jj = 0; jj < 4; ++jj) acc[ii][jj] = (f32x4){0.f, 0.f, 0.f, 0.f};

  int lr8 = lane >> 3;          // row within 8-row group
  int lslot = lane & 7;         // physical 16B slot
  auto stageA = [&](int buf, int k0) {
#pragma unroll
    for (int ii = 0; ii < 4; ++ii) {
      int rg = wid * 4 + ii;            // 8-row group 0..15
      int row = rg * 8 + lr8;
      int ck = lslot ^ (row & 7);
      const unsigned short* src = &alignA[(size_t)(m0 + row) * 512 + k0 + ck * 8];
      __builtin_amdgcn_global_load_lds(
          (const __attribute__((address_space(1))) unsigned int*)src,
          (__attribute__((address_space(3))) unsigned int*)&As[buf][rg * 8][0],
          16, 0, 0);
    }
  };
  auto stageB = [&](int buf, int k0) {
#pragma unroll
    for (int ii = 0; ii < 2; ++ii) {
      int rg = wid * 2 + ii;            // 8-row group 0..7
      int row = rg * 8 + lr8;
      int ck = lslot ^ (row & 7);
      const unsigned short* src = &w_offT[(size_t)(n0 + row) * 512 + k0 + ck * 8];
      __builtin_amdgcn_global_load_lds(
          (const __attribute__((address_space(1))) unsigned int*)src,
          (__attribute__((address_space(3))) unsigned int*)&Bs[buf][rg * 8][0],
          16, 0, 0);
    }
  };

  stageA(0, 0);
  stageB(0, 0);
  __syncthreads();               // vmcnt(0) drain inserted by compiler
  int buf = 0;
  for (int kb = 0; kb < 8; ++kb) {
    if (kb + 1 < 8) {
      stageA(buf ^ 1, (kb + 1) * 64);  // async, flies under compute
      stageB(buf ^ 1, (kb + 1) * 64);
    }
#pragma unroll
    for (int kk = 0; kk < 2; ++kk) {
      int cs = ((kk * 4 + lq) ^ (lrow & 7)) * 8;
      bf16x8 a[2], b[4];
#pragma unroll
      for (int mt = 0; mt < 2; ++mt)
        a[mt] = *(const bf16x8*)&As[buf][wid * 32 + mt * 16 + lrow][cs];
#pragma unroll
      for (int nt = 0; nt < 4; ++nt)
        b[nt] = *(const bf16x8*)&Bs[buf][nt * 16 + lrow][cs];
#pragma unroll
      for (int mt = 0; mt < 2; ++mt)
#pragma unroll
        for (int nt = 0; nt < 4; ++nt)
          acc[mt][nt] = __builtin_amdgcn_mfma_f32_16x16x32_bf16(
              a[mt], b[nt], acc[mt][nt], 0, 0, 0);
    }
    __syncthreads();             // drains next-tile staging; all reads done
    buf ^= 1;
  }
#pragma unroll
  for (int mt = 0; mt < 2; ++mt)
#pragma unroll
    for (int nt = 0; nt < 4; ++nt)
#pragma unroll
      for (int r = 0; r < 4; ++r) {
        int m = m0 + wid * 32 + mt * 16 + lq * 4 + r;
        int n = n0 + nt * 16 + lrow;
        alignBf[(size_t)m * 512 + n] = f2bf(acc[mt][nt][r]);
      }
}

// ---------------------------------------------------------------------------
// Stage 5 (MFMA): om = conv3x3(align) + b_om  as 9 shifted GEMMs.
// R13 (proven 47 us, conflicts 0): M=256 (4 image rows) x N=64 per block ->
// grid 256 = 1 block/CU, one round. 121.5 KB LDS, 128 B rows (conflict-free).
// ---------------------------------------------------------------------------
__global__ __launch_bounds__(256) void om_conv_mfma(
    const unsigned short* __restrict__ alignBf,  // [16384][512] bf16
    const unsigned short* __restrict__ w_omT,    // [9][256 n][512 c] bf16
    const float* __restrict__ b_om,
    float* __restrict__ om) {                    // [16384][216] fp32
  __shared__ unsigned short As[6][66][64];      // 49.5 KB
  __shared__ unsigned short Bs[9][64][64];      // 72 KB
  int i = blockIdx.x;            // flat 0..255
  int xcd = i & 7, j = i >> 3;   // 32 blocks per XCD, contiguous m-band
  int mblk = xcd * 8 + (j >> 2);    // 0..63 (4 image rows each)
  int nblk = j & 3;                 // 0..3
  int b = mblk >> 4, hq = mblk & 15;
  int h0 = hq * 4;
  int n0 = nblk * 64;
  int t = threadIdx.x;
  int wid = t >> 6, lane = t & 63;  // wave = image row h0+wid
  int lrow = lane & 15, lq = lane >> 4;
  const size_t imgbase = (size_t)b * 4096;
  f32x4 acc[4][4];
#pragma unroll
  for (int ii = 0; ii < 4; ++ii)
#pragma unroll
    for (int jj = 0; jj < 4; ++jj) acc[ii][jj] = (f32x4){0.f, 0.f, 0.f, 0.f};

  int lr8 = lane >> 3;   // sub-index within 8-row/8-px group
  int lslot = lane & 7;  // physical 16B slot

  auto stageB = [&](int c0) {
#pragma unroll
    for (int tap = 0; tap < 9; ++tap) {
#pragma unroll
      for (int ii = 0; ii < 2; ++ii) {
        int rg = wid * 2 + ii;            // 8-row group 0..7
        int row = rg * 8 + lr8;
        int ck = lslot ^ lr8;             // row&7 == lr8
        const unsigned short* src =
            &w_omT[((size_t)tap * 256 + n0 + row) * 512 + c0 * 64 + ck * 8];
        __builtin_amdgcn_global_load_lds(
            (const __attribute__((address_space(1))) unsigned int*)src,
            (__attribute__((address_space(3))) unsigned int*)&Bs[tap][rg * 8][0],
            16, 0, 0);
      }
    }
  };
  auto stageA = [&](int c0) {
#pragma unroll
    for (int dy = 0; dy < 6; ++dy) {
      int y = h0 - 1 + dy;
      if (y < 0 || y > 63) continue;      // OOB row stays pre-zeroed
#pragma unroll
      for (int k = 0; k < 2; ++k) {
        int g = wid * 2 + k;              // 8-px group 0..7
        int px0 = 1 + g * 8;
        int px = px0 + lr8;
        int w = g * 8 + lr8;              // px - 1
        int ck = lslot ^ (px & 7);
        const unsigned short* src =
            &alignBf[(imgbase + (size_t)y * 64 + w) * 512 + c0 * 64 + ck * 8];
        __builtin_amdgcn_global_load_lds(
            (const __attribute__((address_space(1))) unsigned int*)src,
            (__attribute__((address_space(3))) unsigned int*)&As[dy][px0][0],
            16, 0, 0);
      }
    }
  };

  // prologue: zero halo cols (px 0,65) for 6 rows, and fully-OOB dy rows.
  {
    uint4 z = make_uint4(0u, 0u, 0u, 0u);
    if (t < 96) {
      int dy = t >> 4;                    // 0..5
      int px = ((t >> 3) & 1) ? 65 : 0;
      int q = t & 7;
      *(uint4*)&As[dy][px][q * 8] = z;
    }
#pragma unroll
    for (int dy = 0; dy < 6; ++dy) {
      int y = h0 - 1 + dy;
      if (y < 0 || y > 63) {
        unsigned short* rowp = &As[dy][0][0];
        for (int u = t; u < 528; u += 256)  // 66*64 shorts = 528 uint4
          *(uint4*)&rowp[u * 8] = z;
      }
    }
  }
  stageA(0);
  stageB(0);

  for (int c0 = 0; c0 < 8; ++c0) {
    __syncthreads();  // drains staging (vmcnt) + zero writes
#pragma unroll
    for (int tap = 0; tap < 9; ++tap) {
      int dyt = tap / 3, dxt = tap - dyt * 3;
#pragma unroll
      for (int kk = 0; kk < 2; ++kk) {
        bf16x8 a[4], bb[4];
#pragma unroll
        for (int mt = 0; mt < 4; ++mt) {
          int prow = mt * 16 + lrow + dxt;
          a[mt] = *(const bf16x8*)&As[wid + dyt][prow][((kk * 4 + lq) ^ (prow & 7)) * 8];
        }
#pragma unroll
        for (int nt = 0; nt < 4; ++nt)
          bb[nt] = *(const bf16x8*)&Bs[tap][nt * 16 + lrow]
                                      [((kk * 4 + lq) ^ (lrow & 7)) * 8];
#pragma unroll
        for (int mt = 0; mt < 4; ++mt)
#pragma unroll
          for (int nt = 0; nt < 4; ++nt)
            acc[mt][nt] = __builtin_amdgcn_mfma_f32_16x16x32_bf16(
                a[mt], bb[nt], acc[mt][nt], 0, 0, 0);
      }
    }
    __syncthreads();  // all reads done before restage
    if (c0 < 7) {
      stageA(c0 + 1);
      stageB(c0 + 1);
    }
  }
  // epilogue: direct store + bias (n < 216)
#pragma unroll
  for (int nt = 0; nt < 4; ++nt) {
    int n = n0 + nt * 16 + lrow;
    if (n < OMC) {
      float bias = b_om[n];
#pragma unroll
      for (int mt = 0; mt < 4; ++mt) {
#pragma unroll
        for (int r = 0; r < 4; ++r) {
          size_t m = imgbase + (size_t)(h0 + wid) * 64 + mt * 16 + lq * 4 + r;
          om[m * OMC + n] = acc[mt][nt][r] + bias;
        }
      }
    }
  }
}

// ---------------------------------------------------------------------------
// Stage 6 (FUSED): deformable sampling + out = relu(S @ w_dcnT + b_dcn) + finecal
// R18: 512 threads (8 waves = 2 waves/SIMD) -- same one-row tile, same
// 112 KB LDS (1 block/CU), but each SIMD now holds TWO waves so gather/LDS/
// VALU latency on one wave hides under the other's MFMA+VALU work.
// Per wave: 32 f (acc[4][2], 16 MFMA/step). Per thread: 4 gathers (8
// threads/px), 1 computeOW entry. T14 issue-early/consume-late retained.
// ---------------------------------------------------------------------------
__global__ __launch_bounds__(512) void dcn_fused(
    const float* __restrict__ om, const unsigned short* __restrict__ upbf,
    const unsigned short* __restrict__ w_dcnT,  // [9][256 f][256 c]
    const float* __restrict__ b_dcn,
    const float* __restrict__ finecal,
    float* __restrict__ outp) {
  __shared__ unsigned short As[2][64][64];    // 16 KB
  __shared__ unsigned short Bs[2][256][64];   // 64 KB
  __shared__ int   offs[2][64][8][4];         // 16 KB
  __shared__ float wts[2][64][8][4];          // 16 KB
  int i = blockIdx.x;            // 0..255
  int xcd = i & 7, j = i >> 3;   // contiguous 32-row band per XCD
  int bh = xcd * 32 + j;         // 0..255 (b*64+h)
  int b = bh >> 6, h = bh & 63;
  const size_t m0 = (size_t)bh * 64;
  const unsigned short* upb = upbf + (size_t)b * HWP * CCH;
  int t = threadIdx.x;           // 0..511
  int wid = t >> 6, lane = t & 63;   // 8 waves; wave wid owns f-range wid*32
  int lrow = lane & 15, lq = lane >> 4;
  f32x4 acc[4][2];
#pragma unroll
  for (int ii = 0; ii < 4; ++ii)
#pragma unroll
    for (int jj = 0; jj < 2; ++jj) acc[ii][jj] = (f32x4){0.f, 0.f, 0.f, 0.f};

  int lr8 = lane >> 3;   // row within 8-row group
  int lslot = lane & 7;  // physical 16B slot
  int px_s = t >> 3, sub_s = t & 7;  // sampling: 8 threads per pixel

  // named gather registers (T14 in-flight state): 4 per thread
  uint4 g0, g1, g2, g3;
  float4 wv;

  // per-tap offsets/weights for all 64 px x 8 groups (512 entries, 1/thread)
  auto computeOW = [&](int owb, int tap) {
    int ky = tap / 3, kx = tap - ky * 3;
    int e = t;  // 512 threads, 512 entries
    {
      int p = e >> 3, gg = e & 7;
      const float* omr = om + (m0 + p) * OMC;
      float dy = omr[gg * 18 + tap * 2];
      float dx = omr[gg * 18 + tap * 2 + 1];
      float mk = 1.0f / (1.0f + expf(-omr[144 + gg * 9 + tap]));
      float sy = (float)(h + ky - 1) + dy;
      float sx = (float)(p + kx - 1) + dx;
      float y0f = floorf(sy), x0f = floorf(sx);
      float fy = sy - y0f, fx = sx - x0f;
      int y0 = (int)y0f, x0 = (int)x0f;
      int y1 = y0 + 1, x1 = x0 + 1;
      float vy0 = (y0 >= 0 && y0 <= 63) ? 1.f : 0.f;
      float vy1 = (y1 >= 0 && y1 <= 63) ? 1.f : 0.f;
      float vx0 = (x0 >= 0 && x0 <= 63) ? 1.f : 0.f;
      float vx1 = (x1 >= 0 && x1 <= 63) ? 1.f : 0.f;
      int yc0 = min(max(y0, 0), 63), yc1 = min(max(y1, 0), 63);
      int xc0 = min(max(x0, 0), 63), xc1 = min(max(x1, 0), 63);
      offs[owb][p][gg][0] = (yc0 * 64 + xc0) * 256;
      offs[owb][p][gg][1] = (yc0 * 64 + xc1) * 256;
      offs[owb][p][gg][2] = (yc1 * 64 + xc0) * 256;
      offs[owb][p][gg][3] = (yc1 * 64 + xc1) * 256;
      wts[owb][p][gg][0] = (1.f - fy) * (1.f - fx) * vy0 * vx0 * mk;
      wts[owb][p][gg][1] = (1.f - fy) * fx * vy0 * vx1 * mk;
      wts[owb][p][gg][2] = fy * (1.f - fx) * vy1 * vx0 * mk;
      wts[owb][p][gg][3] = fy * fx * vy1 * vx1 * mk;
    }
  };

  // stage B[256 f][64 c] for kb via global_load_lds (src-side XOR swizzle)
  auto stageB = [&](int buf, int kb) {
    int tap = kb >> 2, c0 = (kb & 3) * 64;
#pragma unroll
    for (int ii = 0; ii < 4; ++ii) {
      int rg = wid * 4 + ii;            // 8-row group 0..31
      int row = rg * 8 + lr8;
      int ck = lslot ^ (row & 7);
      const unsigned short* src =
          &w_dcnT[((size_t)tap * 256 + row) * 256 + c0 + ck * 8];
      __builtin_amdgcn_global_load_lds(
          (const __attribute__((address_space(1))) unsigned int*)src,
          (__attribute__((address_space(3))) unsigned int*)&Bs[buf][rg * 8][0],
          16, 0, 0);
    }
  };

  // T14 part 1: issue the 4 corner gathers into named registers.
  // Thread covers channels c = c0q*64 + (sub>>2)*32 + (sub&3)*8 (8 channels).
  auto sampleLoad = [&](int kb, int owb) {
    int c0q = kb & 3;
    int g = c0q * 2 + (sub_s >> 2);     // DCN group = channel>>5
    int4 o = *(const int4*)&offs[owb][px_s][g][0];
    wv = *(const float4*)&wts[owb][px_s][g][0];
    int c = c0q * 64 + (sub_s >> 2) * 32 + (sub_s & 3) * 8;
    g0 = *(const uint4*)&upb[o.x + c];
    g1 = *(const uint4*)&upb[o.y + c];
    g2 = *(const uint4*)&upb[o.z + c];
    g3 = *(const uint4*)&upb[o.w + c];
  };
  // T14 part 2: blend + swizzled ds_write (runs after the MFMA cluster).
  // chunk index within the 64-ch quarter = sub_s (verified bijection).
  auto sampleStore = [&](int buf) {
    uint4 res;
    res.x = blend1(g0.x, g1.x, g2.x, g3.x, wv);
    res.y = blend1(g0.y, g1.y, g2.y, g3.y, wv);
    res.z = blend1(g0.z, g1.z, g2.z, g3.z, wv);
    res.w = blend1(g0.w, g1.w, g2.w, g3.w, wv);
    *(uint4*)&As[buf][px_s][(sub_s ^ (px_s & 7)) * 8] = res;
  };

  auto gemmStep = [&](int buf) {
#pragma unroll
    for (int kk = 0; kk < 2; ++kk) {
      int cs = ((kk * 4 + lq) ^ (lrow & 7)) * 8;
      bf16x8 a[4], bv[2];
#pragma unroll
      for (int mt = 0; mt < 4; ++mt)
        a[mt] = *(const bf16x8*)&As[buf][mt * 16 + lrow][cs];
#pragma unroll
      for (int nt = 0; nt < 2; ++nt)
        bv[nt] = *(const bf16x8*)&Bs[buf][wid * 32 + nt * 16 + lrow][cs];
#pragma unroll
      for (int mt = 0; mt < 4; ++mt)
#pragma unroll
        for (int nt = 0; nt < 2; ++nt)
          acc[mt][nt] = __builtin_amdgcn_mfma_f32_16x16x32_bf16(
              a[mt], bv[nt], acc[mt][nt], 0, 0, 0);
    }
  };

  // prologue: ow(0), then stage tile 0 (load + immediate store)
  computeOW(0, 0);
  __syncthreads();              // ow(0) visible
  sampleLoad(0, 0);
  stageB(0, 0);
  sampleStore(0);

  int buf = 0;
  for (int kb = 0; kb < 36; ++kb) {
    int tap = kb >> 2, c0q = kb & 3;
    __syncthreads();            // drains sample writes + stage vmcnt; prior
                                // reads of buf^1 finished -> safe to rewrite
    int nkb = kb + 1;
    if (nkb < 36) {
      sampleLoad(nkb, (nkb >> 2) & 1);  // gathers in flight
      stageB(buf ^ 1, nkb);             // async, under compute
    }
    gemmStep(buf);              // MFMA cluster covers gather latency
    if (c0q == 2 && tap < 8) computeOW((tap + 1) & 1, tap + 1);
    if (nkb < 36) sampleStore(buf ^ 1);
    buf ^= 1;
  }

  // epilogue: out = relu(acc + bias) + finecal
#pragma unroll
  for (int mt = 0; mt < 4; ++mt)
#pragma unroll
    for (int nt = 0; nt < 2; ++nt) {
      int f = wid * 32 + nt * 16 + lrow;
      float bias = b_dcn[f];
#pragma unroll
      for (int r = 0; r < 4; ++r) {
        size_t m = m0 + mt * 16 + lq * 4 + r;
        float v = fmaxf(acc[mt][nt][r] + bias, 0.f);
        float fc = __builtin_nontemporal_load(&finecal[m * 256 + f]);
        __builtin_nontemporal_store(v + fc, &outp[m * 256 + f]);
      }
    }
}

// ---------------------------------------------------------------------------
extern "C" void kernel_launch(void* const* d_in, const int* in_sizes, int n_in,
                              void* d_out, int out_size, void* d_ws, size_t ws_size,
                              hipStream_t stream) {
  const float* coarse = (const float*)d_in[0];
  const float* fine   = (const float*)d_in[1];
  const float* w_att  = (const float*)d_in[2];
  const float* w_sel  = (const float*)d_in[3];
  const float* w_off  = (const float*)d_in[4];
  const float* w_om   = (const float*)d_in[5];
  const float* b_om   = (const float*)d_in[6];
  const float* w_dcn  = (const float*)d_in[7];
  const float* b_dcn  = (const float*)d_in[8];
  float* outp = (float*)d_out;

  char* base = (char*)d_ws;
  size_t o = 0;
  float* scale            = (float*)(base + o);          o += 4096;
  float* finecal          = (float*)(base + o);          o += 16777216;
  float* omb              = (float*)(base + o);          o += 14155776;
  unsigned short* upbf    = (unsigned short*)(base + o); o += 8388608;
  unsigned short* w_offT  = (unsigned short*)(base + o); o += 524288;
  unsigned short* w_omT   = (unsigned short*)(base + o); o += 2359296;  // 9*256*512
  unsigned short* w_selT  = (unsigned short*)(base + o); o += 131072;
  unsigned short* w_dcnT  = (unsigned short*)(base + o); o += 1179648;
  unsigned short* scratch = (unsigned short*)(base + o);  // align region
  // alignA/alignBf live in the former S region (dead by dcn time):
  unsigned short* alignA  = scratch;
  unsigned short* alignBf = (unsigned short*)((char*)scratch + 16777216);
  // partial pooling buffer aliases omb (dead until om_conv writes it)
  float* partial = omb;

  prep_transpose<<<dim3(2048), dim3(256), 0, stream>>>(
      w_off, w_om, w_sel, w_dcn, w_offT, w_omT, w_selT, w_dcnT);
  pool_partial<<<dim3(64, 4), dim3(256), 0, stream>>>(fine, partial);
  pool_finish<<<dim3(4), dim3(256), 0, stream>>>(partial, w_att, scale);
  upsample_kernel<<<dim3(16384), dim3(256), 0, stream>>>(coarse, upbf, alignA);
  gemm_finecal_mfma<<<dim3(512), dim3(256), 0, stream>>>(
      fine, scale, w_selT, finecal, alignA);
  gemm_align_mfma<<<dim3(1024), dim3(256), 0, stream>>>(alignA, w_offT, alignBf);
  om_conv_mfma<<<dim3(256), dim3(256), 0, stream>>>(alignBf, w_omT, b_om, omb);
  dcn_fused<<<dim3(256), dim3(512), 0, stream>>>(
      omb, upbf, w_dcnT, b_dcn, finecal, outp);
}

// Round 14
// 237.540 us; speedup vs baseline: 1.1074x; 1.0118x over previous
//
#include <hip/hip_runtime.h>
#include <hip/hip_bf16.h>
#include <cstddef>

// Shapes (fixed): B=4, H=W=64, C=256, G=8, K=9.
constexpr int HWP = 64 * 64;
constexpr int CCH = 256;
constexpr int OMC = 216;   // G*3*K
constexpr int KDC = 2304;  // 9*256

typedef __attribute__((ext_vector_type(8))) short bf16x8;
typedef __attribute__((ext_vector_type(4))) float f32x4;

__device__ inline unsigned short f2bf(float x) {
  __hip_bfloat16 h = __float2bfloat16(x);
  return *reinterpret_cast<unsigned short*>(&h);
}
__device__ inline float bf2f(unsigned short u) {
  unsigned int v = ((unsigned int)u) << 16;
  return __uint_as_float(v);
}
// unpack a uint holding two bf16: lo -> a, hi -> b
__device__ inline void bfpair(unsigned int u, float& a, float& b) {
  a = __uint_as_float(u << 16);
  b = __uint_as_float(u & 0xffff0000u);
}
// bilinear blend of 4 bf16-pairs with weights wv -> packed bf16 pair
__device__ inline unsigned int blend1(unsigned int ua, unsigned int ub,
                                      unsigned int uc, unsigned int ud,
                                      float4 wv) {
  float a0, a1, b0, b1, c0, c1, d0, d1;
  bfpair(ua, a0, a1); bfpair(ub, b0, b1);
  bfpair(uc, c0, c1); bfpair(ud, d0, d1);
  float v0 = wv.x * a0 + wv.y * b0 + wv.z * c0 + wv.w * d0;
  float v1 = wv.x * a1 + wv.y * b1 + wv.z * c1 + wv.w * d1;
  return (unsigned int)f2bf(v0) | ((unsigned int)f2bf(v1) << 16);
}

// ---------------------------------------------------------------------------
// prep (tiled transpose, coalesced both sides):
//   w_offT[512 n][512 k] ; w_omT[9][256 n(pad)][512 c] ; w_selT[256 n][256 k];
//   w_dcnT[9][256 f][256 c]   (all bf16)
// ---------------------------------------------------------------------------
__global__ __launch_bounds__(256) void prep_transpose(
    const float* __restrict__ w_off, const float* __restrict__ w_om,
    const float* __restrict__ w_sel, const float* __restrict__ w_dcn,
    unsigned short* __restrict__ w_offT, unsigned short* __restrict__ w_omT,
    unsigned short* __restrict__ w_selT, unsigned short* __restrict__ w_dcnT) {
  __shared__ float tile[32][33];
  int bid = blockIdx.x;
  int t = threadIdx.x;
  const float* src;
  unsigned short* dst;
  int in_rs, out_rs, r0, c0, cmax;
  if (bid < 256) {               // w_off: in[512 k][512 n] -> out[n][k]
    int tr = bid >> 4, tc = bid & 15;
    src = w_off; dst = w_offT; in_rs = 512; out_rs = 512;
    r0 = tr * 32; c0 = tc * 32; cmax = 512;
  } else if (bid < 320) {        // w_sel: in[256 k][256 n] -> out[n][k]
    int b2 = bid - 256;
    int tr = b2 >> 3, tc = b2 & 7;
    src = w_sel; dst = w_selT; in_rs = 256; out_rs = 256;
    r0 = tr * 32; c0 = tc * 32; cmax = 256;
  } else if (bid < 896) {        // w_dcn: 9 x in[256 c][256 f] -> out[tap][f][c]
    int b2 = bid - 320;
    int tap = b2 >> 6; b2 &= 63;
    int tr = b2 >> 3, tc = b2 & 7;
    src = w_dcn + (size_t)tap * 65536; dst = w_dcnT + (size_t)tap * 65536;
    in_rs = 256; out_rs = 256;
    r0 = tr * 32; c0 = tc * 32; cmax = 256;
  } else {                       // w_om: 9 x in[512 c][216 n] -> out[tap][256 n][512 c]
    int b2 = bid - 896;
    int tap = b2 >> 7; b2 &= 127;   // 16 r-tiles x 8 c-tiles
    int tr = b2 >> 3, tc = b2 & 7;
    src = w_om + (size_t)tap * 512 * 216; dst = w_omT + (size_t)tap * 256 * 512;
    in_rs = 216; out_rs = 512;
    r0 = tr * 32; c0 = tc * 32; cmax = 216;
  }
  int row = t >> 3, c4 = (t & 7) * 4;
#pragma unroll
  for (int j = 0; j < 4; ++j) {
    int cc = c0 + c4 + j;
    tile[row][c4 + j] = (cc < cmax) ? src[(size_t)(r0 + row) * in_rs + cc] : 0.f;
  }
  __syncthreads();
  ushort4 v;
  v.x = f2bf(tile[c4 + 0][row]);
  v.y = f2bf(tile[c4 + 1][row]);
  v.z = f2bf(tile[c4 + 2][row]);
  v.w = f2bf(tile[c4 + 3][row]);
  *(ushort4*)&dst[(size_t)(c0 + row) * out_rs + r0 + c4] = v;
}

// ---------------------------------------------------------------------------
// Stage 1a/1b: pooled mean (parallel) + attn matvec + sigmoid
// ---------------------------------------------------------------------------
__global__ __launch_bounds__(256) void pool_partial(
    const float* __restrict__ fine, float* __restrict__ partial) {
  int r = blockIdx.x;  // 0..63
  int b = blockIdx.y;  // 0..3
  int t = threadIdx.x;
  const float* src = fine + ((size_t)b * 4096 + r * 64) * 256 + t;
  float s = 0.f;
#pragma unroll 8
  for (int p = 0; p < 64; ++p) s += src[(size_t)p * 256];
  partial[((size_t)b * 64 + r) * 256 + t] = s;
}

__global__ __launch_bounds__(256) void pool_finish(
    const float* __restrict__ partial, const float* __restrict__ w_att,
    float* __restrict__ scale) {
  __shared__ float pl[256];
  int b = blockIdx.x;
  int t = threadIdx.x;
  const float* pp = partial + (size_t)b * 64 * 256 + t;
  float s = 0.f;
#pragma unroll 8
  for (int r = 0; r < 64; ++r) s += pp[(size_t)r * 256];
  pl[t] = s * (1.0f / 4096.0f);
  __syncthreads();
  float acc = 0.f;
  for (int ci = 0; ci < 256; ++ci) acc += pl[ci] * w_att[ci * 256 + t];
  scale[b * 256 + t] = 1.0f + 1.0f / (1.0f + expf(-acc));
}

// ---------------------------------------------------------------------------
// Stage 2: bilinear upsample 32->64 -> upbf (bf16) + 2*up into alignA hi cols
// ---------------------------------------------------------------------------
__global__ __launch_bounds__(256) void upsample_kernel(
    const float* __restrict__ coarse, unsigned short* __restrict__ upbf,
    unsigned short* __restrict__ alignA) {
  int m = blockIdx.x;  // b*4096 + h*64 + w
  int c = threadIdx.x;
  int b = m >> 12, h = (m >> 6) & 63, w = m & 63;
  float cy = fminf(fmaxf(h * 0.5f - 0.25f, 0.f), 31.f);
  float cx = fminf(fmaxf(w * 0.5f - 0.25f, 0.f), 31.f);
  int y0 = (int)cy, x0 = (int)cx;
  float fy = cy - y0, fx = cx - x0;
  int y1 = min(y0 + 1, 31), x1 = min(x0 + 1, 31);
  const float* base = coarse + (size_t)b * 32 * 32 * CCH;
  float v00 = base[(y0 * 32 + x0) * CCH + c];
  float v01 = base[(y0 * 32 + x1) * CCH + c];
  float v10 = base[(y1 * 32 + x0) * CCH + c];
  float v11 = base[(y1 * 32 + x1) * CCH + c];
  float top = v00 + (v01 - v00) * fx;
  float bot = v10 + (v11 - v10) * fx;
  float v = top + (bot - top) * fy;
  upbf[(size_t)m * CCH + c] = f2bf(v);
  alignA[(size_t)m * 512 + 256 + c] = f2bf(2.f * v);
}

// ---------------------------------------------------------------------------
// Stage 3 (MFMA): fine_cal = (fine*scale) @ w_sel -> fp32 finecal (residual)
//                 + bf16 copy into alignA cols 0..255.  Tile 128x64, BK=64.
// XCD-clustered flat grid (A panel per-XCD L2 locality).
// ---------------------------------------------------------------------------
__global__ __launch_bounds__(256) void gemm_finecal_mfma(
    const float* __restrict__ fine, const float* __restrict__ scale,
    const unsigned short* __restrict__ w_selT,   // [256 n][256 k]
    float* __restrict__ finecal, unsigned short* __restrict__ alignA) {
  __shared__ unsigned short As[128][64];
  __shared__ unsigned short Bs[64][64];
  __shared__ float sc[256];
  int i = blockIdx.x;            // flat 0..511
  int xcd = i & 7, j = i >> 3;   // 16 mblk x 4 nblk per XCD
  int mblk = xcd * 16 + (j & 15);   // 0..127
  int nblk = j >> 4;                // 0..3
  int n0 = nblk * 64;
  int m0 = mblk * 128;
  int t = threadIdx.x;
  int wid = t >> 6, lane = t & 63;
  int lrow = lane & 15, lq = lane >> 4;
  int bb = m0 >> 12;  // 128 | 4096: no batch straddle
  sc[t] = scale[bb * 256 + t];
  f32x4 acc[2][4];
#pragma unroll
  for (int ii = 0; ii < 2; ++ii)
#pragma unroll
    for (int jj = 0; jj < 4; ++jj) acc[ii][jj] = (f32x4){0.f, 0.f, 0.f, 0.f};
  for (int k0 = 0; k0 < 256; k0 += 64) {
    __syncthreads();  // also covers sc[] on first iteration
    for (int u = t; u < 128 * 8; u += 256) {
      int row = u >> 3, ck = u & 7;
      const float* fp = &fine[(size_t)(m0 + row) * 256 + k0 + ck * 8];
      float4 f0 = *(const float4*)fp;
      float4 f1 = *(const float4*)(fp + 4);
      int kb = k0 + ck * 8;
      ushort4 u0 = make_ushort4(f2bf(f0.x * sc[kb]), f2bf(f0.y * sc[kb + 1]),
                                f2bf(f0.z * sc[kb + 2]), f2bf(f0.w * sc[kb + 3]));
      ushort4 u1 = make_ushort4(f2bf(f1.x * sc[kb + 4]), f2bf(f1.y * sc[kb + 5]),
                                f2bf(f1.z * sc[kb + 6]), f2bf(f1.w * sc[kb + 7]));
      int cb = (ck ^ (row & 7)) * 8;
      *(ushort4*)&As[row][cb] = u0;
      *(ushort4*)&As[row][cb + 4] = u1;
    }
    for (int u = t; u < 64 * 8; u += 256) {
      int row = u >> 3, ck = u & 7;
      *(uint4*)&Bs[row][(ck ^ (row & 7)) * 8] =
          *(const uint4*)&w_selT[(size_t)(n0 + row) * 256 + k0 + ck * 8];
    }
    __syncthreads();
#pragma unroll
    for (int kk = 0; kk < 2; ++kk) {
      int cs = ((kk * 4 + lq) ^ (lrow & 7)) * 8;
      bf16x8 a[2], b[4];
#pragma unroll
      for (int mt = 0; mt < 2; ++mt)
        a[mt] = *(const bf16x8*)&As[wid * 32 + mt * 16 + lrow][cs];
#pragma unroll
      for (int nt = 0; nt < 4; ++nt)
        b[nt] = *(const bf16x8*)&Bs[nt * 16 + lrow][cs];
#pragma unroll
      for (int mt = 0; mt < 2; ++mt)
#pragma unroll
        for (int nt = 0; nt < 4; ++nt)
          acc[mt][nt] = __builtin_amdgcn_mfma_f32_16x16x32_bf16(
              a[mt], b[nt], acc[mt][nt], 0, 0, 0);
    }
  }
#pragma unroll
  for (int mt = 0; mt < 2; ++mt)
#pragma unroll
    for (int nt = 0; nt < 4; ++nt)
#pragma unroll
      for (int r = 0; r < 4; ++r) {
        int m = m0 + wid * 32 + mt * 16 + lq * 4 + r;
        int n = n0 + nt * 16 + lrow;
        finecal[(size_t)m * 256 + n] = acc[mt][nt][r];
        alignA[(size_t)m * 512 + n] = f2bf(acc[mt][nt][r]);
      }
}

// ---------------------------------------------------------------------------
// Stage 4 (MFMA): align = alignA @ w_off -> bf16 [16384][512]
// gload_lds issue-early double-buffer + XCD-clustered flat grid.
// ---------------------------------------------------------------------------
__global__ __launch_bounds__(256) void gemm_align_mfma(
    const unsigned short* __restrict__ alignA,
    const unsigned short* __restrict__ w_offT,
    unsigned short* __restrict__ alignBf) {
  __shared__ unsigned short As[2][128][64];     // 32 KB
  __shared__ unsigned short Bs[2][64][64];      // 16 KB
  int i = blockIdx.x;            // flat 0..1023
  int xcd = i & 7, j = i >> 3;   // 16 mblk x 8 nblk per XCD
  int mblk = xcd * 16 + (j & 15);   // 0..127
  int nblk = j >> 4;                // 0..7
  int n0 = nblk * 64;
  int m0 = mblk * 128;
  int t = threadIdx.x;
  int wid = t >> 6, lane = t & 63;
  int lrow = lane & 15, lq = lane >> 4;
  f32x4 acc[2][4];
#pragma unroll
  for (int ii = 0; ii < 2; ++ii)
#pragma unroll
    for (int jj = 0; jj < 4; ++jj) acc[ii][jj] = (f32x4){0.f, 0.f, 0.f, 0.f};

  int lr8 = lane >> 3;          // row within 8-row group
  int lslot = lane & 7;         // physical 16B slot
  auto stageA = [&](int buf, int k0) {
#pragma unroll
    for (int ii = 0; ii < 4; ++ii) {
      int rg = wid * 4 + ii;            // 8-row group 0..15
      int row = rg * 8 + lr8;
      int ck = lslot ^ (row & 7);
      const unsigned short* src = &alignA[(size_t)(m0 + row) * 512 + k0 + ck * 8];
      __builtin_amdgcn_global_load_lds(
          (const __attribute__((address_space(1))) unsigned int*)src,
          (__attribute__((address_space(3))) unsigned int*)&As[buf][rg * 8][0],
          16, 0, 0);
    }
  };
  auto stageB = [&](int buf, int k0) {
#pragma unroll
    for (int ii = 0; ii < 2; ++ii) {
      int rg = wid * 2 + ii;            // 8-row group 0..7
      int row = rg * 8 + lr8;
      int ck = lslot ^ (row & 7);
      const unsigned short* src = &w_offT[(size_t)(n0 + row) * 512 + k0 + ck * 8];
      __builtin_amdgcn_global_load_lds(
          (const __attribute__((address_space(1))) unsigned int*)src,
          (__attribute__((address_space(3))) unsigned int*)&Bs[buf][rg * 8][0],
          16, 0, 0);
    }
  };

  stageA(0, 0);
  stageB(0, 0);
  __syncthreads();               // vmcnt(0) drain inserted by compiler
  int buf = 0;
  for (int kb = 0; kb < 8; ++kb) {
    if (kb + 1 < 8) {
      stageA(buf ^ 1, (kb + 1) * 64);  // async, flies under compute
      stageB(buf ^ 1, (kb + 1) * 64);
    }
#pragma unroll
    for (int kk = 0; kk < 2; ++kk) {
      int cs = ((kk * 4 + lq) ^ (lrow & 7)) * 8;
      bf16x8 a[2], b[4];
#pragma unroll
      for (int mt = 0; mt < 2; ++mt)
        a[mt] = *(const bf16x8*)&As[buf][wid * 32 + mt * 16 + lrow][cs];
#pragma unroll
      for (int nt = 0; nt < 4; ++nt)
        b[nt] = *(const bf16x8*)&Bs[buf][nt * 16 + lrow][cs];
#pragma unroll
      for (int mt = 0; mt < 2; ++mt)
#pragma unroll
        for (int nt = 0; nt < 4; ++nt)
          acc[mt][nt] = __builtin_amdgcn_mfma_f32_16x16x32_bf16(
              a[mt], b[nt], acc[mt][nt], 0, 0, 0);
    }
    __syncthreads();             // drains next-tile staging; all reads done
    buf ^= 1;
  }
#pragma unroll
  for (int mt = 0; mt < 2; ++mt)
#pragma unroll
    for (int nt = 0; nt < 4; ++nt)
#pragma unroll
      for (int r = 0; r < 4; ++r) {
        int m = m0 + wid * 32 + mt * 16 + lq * 4 + r;
        int n = n0 + nt * 16 + lrow;
        alignBf[(size_t)m * 512 + n] = f2bf(acc[mt][nt][r]);
      }
}

// ---------------------------------------------------------------------------
// Stage 5 (MFMA): om = conv3x3(align) + b_om  as 9 shifted GEMMs.
// R13 (proven 47 us, conflicts 0): M=256 (4 image rows) x N=64 per block ->
// grid 256 = 1 block/CU, one round. 121.5 KB LDS, 128 B rows (conflict-free).
// ---------------------------------------------------------------------------
__global__ __launch_bounds__(256) void om_conv_mfma(
    const unsigned short* __restrict__ alignBf,  // [16384][512] bf16
    const unsigned short* __restrict__ w_omT,    // [9][256 n][512 c] bf16
    const float* __restrict__ b_om,
    float* __restrict__ om) {                    // [16384][216] fp32
  __shared__ unsigned short As[6][66][64];      // 49.5 KB
  __shared__ unsigned short Bs[9][64][64];      // 72 KB
  int i = blockIdx.x;            // flat 0..255
  int xcd = i & 7, j = i >> 3;   // 32 blocks per XCD, contiguous m-band
  int mblk = xcd * 8 + (j >> 2);    // 0..63 (4 image rows each)
  int nblk = j & 3;                 // 0..3
  int b = mblk >> 4, hq = mblk & 15;
  int h0 = hq * 4;
  int n0 = nblk * 64;
  int t = threadIdx.x;
  int wid = t >> 6, lane = t & 63;  // wave = image row h0+wid
  int lrow = lane & 15, lq = lane >> 4;
  const size_t imgbase = (size_t)b * 4096;
  f32x4 acc[4][4];
#pragma unroll
  for (int ii = 0; ii < 4; ++ii)
#pragma unroll
    for (int jj = 0; jj < 4; ++jj) acc[ii][jj] = (f32x4){0.f, 0.f, 0.f, 0.f};

  int lr8 = lane >> 3;   // sub-index within 8-row/8-px group
  int lslot = lane & 7;  // physical 16B slot

  auto stageB = [&](int c0) {
#pragma unroll
    for (int tap = 0; tap < 9; ++tap) {
#pragma unroll
      for (int ii = 0; ii < 2; ++ii) {
        int rg = wid * 2 + ii;            // 8-row group 0..7
        int row = rg * 8 + lr8;
        int ck = lslot ^ lr8;             // row&7 == lr8
        const unsigned short* src =
            &w_omT[((size_t)tap * 256 + n0 + row) * 512 + c0 * 64 + ck * 8];
        __builtin_amdgcn_global_load_lds(
            (const __attribute__((address_space(1))) unsigned int*)src,
            (__attribute__((address_space(3))) unsigned int*)&Bs[tap][rg * 8][0],
            16, 0, 0);
      }
    }
  };
  auto stageA = [&](int c0) {
#pragma unroll
    for (int dy = 0; dy < 6; ++dy) {
      int y = h0 - 1 + dy;
      if (y < 0 || y > 63) continue;      // OOB row stays pre-zeroed
#pragma unroll
      for (int k = 0; k < 2; ++k) {
        int g = wid * 2 + k;              // 8-px group 0..7
        int px0 = 1 + g * 8;
        int px = px0 + lr8;
        int w = g * 8 + lr8;              // px - 1
        int ck = lslot ^ (px & 7);
        const unsigned short* src =
            &alignBf[(imgbase + (size_t)y * 64 + w) * 512 + c0 * 64 + ck * 8];
        __builtin_amdgcn_global_load_lds(
            (const __attribute__((address_space(1))) unsigned int*)src,
            (__attribute__((address_space(3))) unsigned int*)&As[dy][px0][0],
            16, 0, 0);
      }
    }
  };

  // prologue: zero halo cols (px 0,65) for 6 rows, and fully-OOB dy rows.
  {
    uint4 z = make_uint4(0u, 0u, 0u, 0u);
    if (t < 96) {
      int dy = t >> 4;                    // 0..5
      int px = ((t >> 3) & 1) ? 65 : 0;
      int q = t & 7;
      *(uint4*)&As[dy][px][q * 8] = z;
    }
#pragma unroll
    for (int dy = 0; dy < 6; ++dy) {
      int y = h0 - 1 + dy;
      if (y < 0 || y > 63) {
        unsigned short* rowp = &As[dy][0][0];
        for (int u = t; u < 528; u += 256)  // 66*64 shorts = 528 uint4
          *(uint4*)&rowp[u * 8] = z;
      }
    }
  }
  stageA(0);
  stageB(0);

  for (int c0 = 0; c0 < 8; ++c0) {
    __syncthreads();  // drains staging (vmcnt) + zero writes
#pragma unroll
    for (int tap = 0; tap < 9; ++tap) {
      int dyt = tap / 3, dxt = tap - dyt * 3;
#pragma unroll
      for (int kk = 0; kk < 2; ++kk) {
        bf16x8 a[4], bb[4];
#pragma unroll
        for (int mt = 0; mt < 4; ++mt) {
          int prow = mt * 16 + lrow + dxt;
          a[mt] = *(const bf16x8*)&As[wid + dyt][prow][((kk * 4 + lq) ^ (prow & 7)) * 8];
        }
#pragma unroll
        for (int nt = 0; nt < 4; ++nt)
          bb[nt] = *(const bf16x8*)&Bs[tap][nt * 16 + lrow]
                                      [((kk * 4 + lq) ^ (lrow & 7)) * 8];
#pragma unroll
        for (int mt = 0; mt < 4; ++mt)
#pragma unroll
          for (int nt = 0; nt < 4; ++nt)
            acc[mt][nt] = __builtin_amdgcn_mfma_f32_16x16x32_bf16(
                a[mt], bb[nt], acc[mt][nt], 0, 0, 0);
      }
    }
    __syncthreads();  // all reads done before restage
    if (c0 < 7) {
      stageA(c0 + 1);
      stageB(c0 + 1);
    }
  }
  // epilogue: direct store + bias (n < 216)
#pragma unroll
  for (int nt = 0; nt < 4; ++nt) {
    int n = n0 + nt * 16 + lrow;
    if (n < OMC) {
      float bias = b_om[n];
#pragma unroll
      for (int mt = 0; mt < 4; ++mt) {
#pragma unroll
        for (int r = 0; r < 4; ++r) {
          size_t m = imgbase + (size_t)(h0 + wid) * 64 + mt * 16 + lq * 4 + r;
          om[m * OMC + n] = acc[mt][nt][r] + bias;
        }
      }
    }
  }
}

// ---------------------------------------------------------------------------
// Stage 6 (FUSED): deformable sampling + out = relu(S @ w_dcnT + b_dcn) + finecal
// R19: 1024 threads (16 waves = 4 waves/SIMD), same 112 KB LDS, 1 block/CU,
// grid 256 (all CUs). Role split:
//   waves 0-7: sampling (R13 decomposition: 8 thr/px, 4 gathers, T14 split)
//              + computeOW;
//   waves 8-15: all B staging (4 gload_lds each).
// GEMM: 16 waves = 2 m-halves x 8 f-slices; wave owns 32 px x 32 f
// (acc[2][2], 8 MFMA + 8 ds_read/step). Barrier/buffer logic identical R13.
// ---------------------------------------------------------------------------
__global__ __launch_bounds__(1024) void dcn_fused(
    const float* __restrict__ om, const unsigned short* __restrict__ upbf,
    const unsigned short* __restrict__ w_dcnT,  // [9][256 f][256 c]
    const float* __restrict__ b_dcn,
    const float* __restrict__ finecal,
    float* __restrict__ outp) {
  __shared__ unsigned short As[2][64][64];    // 16 KB
  __shared__ unsigned short Bs[2][256][64];   // 64 KB
  __shared__ int   offs[2][64][8][4];         // 16 KB
  __shared__ float wts[2][64][8][4];          // 16 KB
  int i = blockIdx.x;            // 0..255
  int xcd = i & 7, j = i >> 3;   // contiguous 32-row band per XCD
  int bh = xcd * 32 + j;         // 0..255 (b*64+h)
  int b = bh >> 6, h = bh & 63;
  const size_t m0 = (size_t)bh * 64;
  const unsigned short* upb = upbf + (size_t)b * HWP * CCH;
  int t = threadIdx.x;           // 0..1023
  int wid = t >> 6, lane = t & 63;   // 16 waves
  int lrow = lane & 15, lq = lane >> 4;
  int mh = wid >> 3;             // m-half 0..1 (rows mh*32..)
  int fi = wid & 7;              // f-slice 0..7 (f = fi*32..)
  bool sampler = (wid < 8);      // waves 0-7 sample; 8-15 stage B
  f32x4 acc[2][2];
#pragma unroll
  for (int ii = 0; ii < 2; ++ii)
#pragma unroll
    for (int jj = 0; jj < 2; ++jj) acc[ii][jj] = (f32x4){0.f, 0.f, 0.f, 0.f};

  int lr8 = lane >> 3;   // row within 8-row group
  int lslot = lane & 7;  // physical 16B slot
  int px_s = (t & 511) >> 3, sub_s = t & 7;  // sampling decomposition (t<512)

  // named gather registers (T14 in-flight state): 4 per sampler thread
  uint4 g0, g1, g2, g3;
  float4 wv;

  // per-tap offsets/weights for all 64 px x 8 groups (512 entries; t<512)
  auto computeOW = [&](int owb, int tap) {
    if (t >= 512) return;              // wave-uniform (waves 0-7 only)
    int ky = tap / 3, kx = tap - ky * 3;
    int e = t;
    {
      int p = e >> 3, gg = e & 7;
      const float* omr = om + (m0 + p) * OMC;
      float dy = omr[gg * 18 + tap * 2];
      float dx = omr[gg * 18 + tap * 2 + 1];
      float mk = 1.0f / (1.0f + expf(-omr[144 + gg * 9 + tap]));
      float sy = (float)(h + ky - 1) + dy;
      float sx = (float)(p + kx - 1) + dx;
      float y0f = floorf(sy), x0f = floorf(sx);
      float fy = sy - y0f, fx = sx - x0f;
      int y0 = (int)y0f, x0 = (int)x0f;
      int y1 = y0 + 1, x1 = x0 + 1;
      float vy0 = (y0 >= 0 && y0 <= 63) ? 1.f : 0.f;
      float vy1 = (y1 >= 0 && y1 <= 63) ? 1.f : 0.f;
      float vx0 = (x0 >= 0 && x0 <= 63) ? 1.f : 0.f;
      float vx1 = (x1 >= 0 && x1 <= 63) ? 1.f : 0.f;
      int yc0 = min(max(y0, 0), 63), yc1 = min(max(y1, 0), 63);
      int xc0 = min(max(x0, 0), 63), xc1 = min(max(x1, 0), 63);
      offs[owb][p][gg][0] = (yc0 * 64 + xc0) * 256;
      offs[owb][p][gg][1] = (yc0 * 64 + xc1) * 256;
      offs[owb][p][gg][2] = (yc1 * 64 + xc0) * 256;
      offs[owb][p][gg][3] = (yc1 * 64 + xc1) * 256;
      wts[owb][p][gg][0] = (1.f - fy) * (1.f - fx) * vy0 * vx0 * mk;
      wts[owb][p][gg][1] = (1.f - fy) * fx * vy0 * vx1 * mk;
      wts[owb][p][gg][2] = fy * (1.f - fx) * vy1 * vx0 * mk;
      wts[owb][p][gg][3] = fy * fx * vy1 * vx1 * mk;
    }
  };

  // stage B[256 f][64 c] for kb via global_load_lds (waves 8-15; 32 loads)
  auto stageB = [&](int buf, int kb) {
    if (wid < 8) return;               // wave-uniform
    int tap = kb >> 2, c0 = (kb & 3) * 64;
    int w8 = wid - 8;
#pragma unroll
    for (int ii = 0; ii < 4; ++ii) {
      int rg = w8 * 4 + ii;             // 8-row group 0..31
      int row = rg * 8 + lr8;
      int ck = lslot ^ (row & 7);
      const unsigned short* src =
          &w_dcnT[((size_t)tap * 256 + row) * 256 + c0 + ck * 8];
      __builtin_amdgcn_global_load_lds(
          (const __attribute__((address_space(1))) unsigned int*)src,
          (__attribute__((address_space(3))) unsigned int*)&Bs[buf][rg * 8][0],
          16, 0, 0);
    }
  };

  // T14 part 1: issue the 4 corner gathers into named registers (waves 0-7).
  auto sampleLoad = [&](int kb, int owb) {
    if (!sampler) return;
    int c0q = kb & 3;
    int g = c0q * 2 + (sub_s >> 2);     // DCN group = channel>>5
    int4 o = *(const int4*)&offs[owb][px_s][g][0];
    wv = *(const float4*)&wts[owb][px_s][g][0];
    int c = c0q * 64 + (sub_s >> 2) * 32 + (sub_s & 3) * 8;
    g0 = *(const uint4*)&upb[o.x + c];
    g1 = *(const uint4*)&upb[o.y + c];
    g2 = *(const uint4*)&upb[o.z + c];
    g3 = *(const uint4*)&upb[o.w + c];
  };
  // T14 part 2: blend + swizzled ds_write (runs after the MFMA cluster).
  auto sampleStore = [&](int buf) {
    if (!sampler) return;
    uint4 res;
    res.x = blend1(g0.x, g1.x, g2.x, g3.x, wv);
    res.y = blend1(g0.y, g1.y, g2.y, g3.y, wv);
    res.z = blend1(g0.z, g1.z, g2.z, g3.z, wv);
    res.w = blend1(g0.w, g1.w, g2.w, g3.w, wv);
    *(uint4*)&As[buf][px_s][(sub_s ^ (px_s & 7)) * 8] = res;
  };

  auto gemmStep = [&](int buf) {
#pragma unroll
    for (int kk = 0; kk < 2; ++kk) {
      int cs = ((kk * 4 + lq) ^ (lrow & 7)) * 8;
      bf16x8 a[2], bv[2];
#pragma unroll
      for (int mt = 0; mt < 2; ++mt)
        a[mt] = *(const bf16x8*)&As[buf][mh * 32 + mt * 16 + lrow][cs];
#pragma unroll
      for (int nt = 0; nt < 2; ++nt)
        bv[nt] = *(const bf16x8*)&Bs[buf][fi * 32 + nt * 16 + lrow][cs];
#pragma unroll
      for (int mt = 0; mt < 2; ++mt)
#pragma unroll
        for (int nt = 0; nt < 2; ++nt)
          acc[mt][nt] = __builtin_amdgcn_mfma_f32_16x16x32_bf16(
              a[mt], bv[nt], acc[mt][nt], 0, 0, 0);
    }
  };

  // prologue: ow(0), then stage tile 0 (load + immediate store)
  computeOW(0, 0);
  __syncthreads();              // ow(0) visible
  sampleLoad(0, 0);
  stageB(0, 0);
  sampleStore(0);

  int buf = 0;
  for (int kb = 0; kb < 36; ++kb) {
    int tap = kb >> 2, c0q = kb & 3;
    __syncthreads();            // drains sample writes + stage vmcnt; prior
                                // reads of buf^1 finished -> safe to rewrite
    int nkb = kb + 1;
    if (nkb < 36) {
      sampleLoad(nkb, (nkb >> 2) & 1);  // gathers in flight
      stageB(buf ^ 1, nkb);             // async, under compute
    }
    gemmStep(buf);              // MFMA cluster covers gather latency
    if (c0q == 2 && tap < 8) computeOW((tap + 1) & 1, tap + 1);
    if (nkb < 36) sampleStore(buf ^ 1);
    buf ^= 1;
  }

  // epilogue: out = relu(acc + bias) + finecal
#pragma unroll
  for (int mt = 0; mt < 2; ++mt)
#pragma unroll
    for (int nt = 0; nt < 2; ++nt) {
      int f = fi * 32 + nt * 16 + lrow;
      float bias = b_dcn[f];
#pragma unroll
      for (int r = 0; r < 4; ++r) {
        size_t m = m0 + mh * 32 + mt * 16 + lq * 4 + r;
        float v = fmaxf(acc[mt][nt][r] + bias, 0.f);
        float fc = __builtin_nontemporal_load(&finecal[m * 256 + f]);
        __builtin_nontemporal_store(v + fc, &outp[m * 256 + f]);
      }
    }
}

// ---------------------------------------------------------------------------
extern "C" void kernel_launch(void* const* d_in, const int* in_sizes, int n_in,
                              void* d_out, int out_size, void* d_ws, size_t ws_size,
                              hipStream_t stream) {
  const float* coarse = (const float*)d_in[0];
  const float* fine   = (const float*)d_in[1];
  const float* w_att  = (const float*)d_in[2];
  const float* w_sel  = (const float*)d_in[3];
  const float* w_off  = (const float*)d_in[4];
  const float* w_om   = (const float*)d_in[5];
  const float* b_om   = (const float*)d_in[6];
  const float* w_dcn  = (const float*)d_in[7];
  const float* b_dcn  = (const float*)d_in[8];
  float* outp = (float*)d_out;

  char* base = (char*)d_ws;
  size_t o = 0;
  float* scale            = (float*)(base + o);          o += 4096;
  float* finecal          = (float*)(base + o);          o += 16777216;
  float* omb              = (float*)(base + o);          o += 14155776;
  unsigned short* upbf    = (unsigned short*)(base + o); o += 8388608;
  unsigned short* w_offT  = (unsigned short*)(base + o); o += 524288;
  unsigned short* w_omT   = (unsigned short*)(base + o); o += 2359296;  // 9*256*512
  unsigned short* w_selT  = (unsigned short*)(base + o); o += 131072;
  unsigned short* w_dcnT  = (unsigned short*)(base + o); o += 1179648;
  unsigned short* scratch = (unsigned short*)(base + o);  // align region
  // alignA/alignBf live in the former S region (dead by dcn time):
  unsigned short* alignA  = scratch;
  unsigned short* alignBf = (unsigned short*)((char*)scratch + 16777216);
  // partial pooling buffer aliases omb (dead until om_conv writes it)
  float* partial = omb;

  prep_transpose<<<dim3(2048), dim3(256), 0, stream>>>(
      w_off, w_om, w_sel, w_dcn, w_offT, w_omT, w_selT, w_dcnT);
  pool_partial<<<dim3(64, 4), dim3(256), 0, stream>>>(fine, partial);
  pool_finish<<<dim3(4), dim3(256), 0, stream>>>(partial, w_att, scale);
  upsample_kernel<<<dim3(16384), dim3(256), 0, stream>>>(coarse, upbf, alignA);
  gemm_finecal_mfma<<<dim3(512), dim3(256), 0, stream>>>(
      fine, scale, w_selT, finecal, alignA);
  gemm_align_mfma<<<dim3(1024), dim3(256), 0, stream>>>(alignA, w_offT, alignBf);
  om_conv_mfma<<<dim3(256), dim3(256), 0, stream>>>(alignBf, w_omT, b_om, omb);
  dcn_fused<<<dim3(256), dim3(1024), 0, stream>>>(
      omb, upbf, w_dcnT, b_dcn, finecal, outp);
}

// Round 15
// 227.989 us; speedup vs baseline: 1.1538x; 1.0419x over previous
//
#include <hip/hip_runtime.h>
#include <hip/hip_bf16.h>
#include <cstddef>

// Shapes (fixed): B=4, H=W=64, C=256, G=8, K=9.
constexpr int HWP = 64 * 64;
constexpr int CCH = 256;
constexpr int OMC = 216;   // G*3*K
constexpr int KDC = 2304;  // 9*256

typedef __attribute__((ext_vector_type(8))) short bf16x8;
typedef __attribute__((ext_vector_type(4))) float f32x4;

__device__ inline unsigned short f2bf(float x) {
  __hip_bfloat16 h = __float2bfloat16(x);
  return *reinterpret_cast<unsigned short*>(&h);
}
__device__ inline float bf2f(unsigned short u) {
  unsigned int v = ((unsigned int)u) << 16;
  return __uint_as_float(v);
}
// unpack a uint holding two bf16: lo -> a, hi -> b
__device__ inline void bfpair(unsigned int u, float& a, float& b) {
  a = __uint_as_float(u << 16);
  b = __uint_as_float(u & 0xffff0000u);
}
// bilinear blend of 4 bf16-pairs with weights wv -> packed bf16 pair
__device__ inline unsigned int blend1(unsigned int ua, unsigned int ub,
                                      unsigned int uc, unsigned int ud,
                                      float4 wv) {
  float a0, a1, b0, b1, c0, c1, d0, d1;
  bfpair(ua, a0, a1); bfpair(ub, b0, b1);
  bfpair(uc, c0, c1); bfpair(ud, d0, d1);
  float v0 = wv.x * a0 + wv.y * b0 + wv.z * c0 + wv.w * d0;
  float v1 = wv.x * a1 + wv.y * b1 + wv.z * c1 + wv.w * d1;
  return (unsigned int)f2bf(v0) | ((unsigned int)f2bf(v1) << 16);
}

// ---------------------------------------------------------------------------
// prep (tiled transpose, coalesced both sides):
//   w_offT[512 n][512 k] ; w_omT[9][256 n(pad)][512 c] ; w_selT[256 n][256 k];
//   w_dcnT[9][256 f][256 c]   (all bf16)
// ---------------------------------------------------------------------------
__global__ __launch_bounds__(256) void prep_transpose(
    const float* __restrict__ w_off, const float* __restrict__ w_om,
    const float* __restrict__ w_sel, const float* __restrict__ w_dcn,
    unsigned short* __restrict__ w_offT, unsigned short* __restrict__ w_omT,
    unsigned short* __restrict__ w_selT, unsigned short* __restrict__ w_dcnT) {
  __shared__ float tile[32][33];
  int bid = blockIdx.x;
  int t = threadIdx.x;
  const float* src;
  unsigned short* dst;
  int in_rs, out_rs, r0, c0, cmax;
  if (bid < 256) {               // w_off: in[512 k][512 n] -> out[n][k]
    int tr = bid >> 4, tc = bid & 15;
    src = w_off; dst = w_offT; in_rs = 512; out_rs = 512;
    r0 = tr * 32; c0 = tc * 32; cmax = 512;
  } else if (bid < 320) {        // w_sel: in[256 k][256 n] -> out[n][k]
    int b2 = bid - 256;
    int tr = b2 >> 3, tc = b2 & 7;
    src = w_sel; dst = w_selT; in_rs = 256; out_rs = 256;
    r0 = tr * 32; c0 = tc * 32; cmax = 256;
  } else if (bid < 896) {        // w_dcn: 9 x in[256 c][256 f] -> out[tap][f][c]
    int b2 = bid - 320;
    int tap = b2 >> 6; b2 &= 63;
    int tr = b2 >> 3, tc = b2 & 7;
    src = w_dcn + (size_t)tap * 65536; dst = w_dcnT + (size_t)tap * 65536;
    in_rs = 256; out_rs = 256;
    r0 = tr * 32; c0 = tc * 32; cmax = 256;
  } else {                       // w_om: 9 x in[512 c][216 n] -> out[tap][256 n][512 c]
    int b2 = bid - 896;
    int tap = b2 >> 7; b2 &= 127;   // 16 r-tiles x 8 c-tiles
    int tr = b2 >> 3, tc = b2 & 7;
    src = w_om + (size_t)tap * 512 * 216; dst = w_omT + (size_t)tap * 256 * 512;
    in_rs = 216; out_rs = 512;
    r0 = tr * 32; c0 = tc * 32; cmax = 216;
  }
  int row = t >> 3, c4 = (t & 7) * 4;
#pragma unroll
  for (int j = 0; j < 4; ++j) {
    int cc = c0 + c4 + j;
    tile[row][c4 + j] = (cc < cmax) ? src[(size_t)(r0 + row) * in_rs + cc] : 0.f;
  }
  __syncthreads();
  ushort4 v;
  v.x = f2bf(tile[c4 + 0][row]);
  v.y = f2bf(tile[c4 + 1][row]);
  v.z = f2bf(tile[c4 + 2][row]);
  v.w = f2bf(tile[c4 + 3][row]);
  *(ushort4*)&dst[(size_t)(c0 + row) * out_rs + r0 + c4] = v;
}

// ---------------------------------------------------------------------------
// Stage 1a/1b: pooled mean (parallel) + attn matvec + sigmoid
// ---------------------------------------------------------------------------
__global__ __launch_bounds__(256) void pool_partial(
    const float* __restrict__ fine, float* __restrict__ partial) {
  int r = blockIdx.x;  // 0..63
  int b = blockIdx.y;  // 0..3
  int t = threadIdx.x;
  const float* src = fine + ((size_t)b * 4096 + r * 64) * 256 + t;
  float s = 0.f;
#pragma unroll 8
  for (int p = 0; p < 64; ++p) s += src[(size_t)p * 256];
  partial[((size_t)b * 64 + r) * 256 + t] = s;
}

__global__ __launch_bounds__(256) void pool_finish(
    const float* __restrict__ partial, const float* __restrict__ w_att,
    float* __restrict__ scale) {
  __shared__ float pl[256];
  int b = blockIdx.x;
  int t = threadIdx.x;
  const float* pp = partial + (size_t)b * 64 * 256 + t;
  float s = 0.f;
#pragma unroll 8
  for (int r = 0; r < 64; ++r) s += pp[(size_t)r * 256];
  pl[t] = s * (1.0f / 4096.0f);
  __syncthreads();
  float acc = 0.f;
  for (int ci = 0; ci < 256; ++ci) acc += pl[ci] * w_att[ci * 256 + t];
  scale[b * 256 + t] = 1.0f + 1.0f / (1.0f + expf(-acc));
}

// ---------------------------------------------------------------------------
// Stage 2: bilinear upsample 32->64 -> upbf (bf16) + 2*up into alignA hi cols
// ---------------------------------------------------------------------------
__global__ __launch_bounds__(256) void upsample_kernel(
    const float* __restrict__ coarse, unsigned short* __restrict__ upbf,
    unsigned short* __restrict__ alignA) {
  int m = blockIdx.x;  // b*4096 + h*64 + w
  int c = threadIdx.x;
  int b = m >> 12, h = (m >> 6) & 63, w = m & 63;
  float cy = fminf(fmaxf(h * 0.5f - 0.25f, 0.f), 31.f);
  float cx = fminf(fmaxf(w * 0.5f - 0.25f, 0.f), 31.f);
  int y0 = (int)cy, x0 = (int)cx;
  float fy = cy - y0, fx = cx - x0;
  int y1 = min(y0 + 1, 31), x1 = min(x0 + 1, 31);
  const float* base = coarse + (size_t)b * 32 * 32 * CCH;
  float v00 = base[(y0 * 32 + x0) * CCH + c];
  float v01 = base[(y0 * 32 + x1) * CCH + c];
  float v10 = base[(y1 * 32 + x0) * CCH + c];
  float v11 = base[(y1 * 32 + x1) * CCH + c];
  float top = v00 + (v01 - v00) * fx;
  float bot = v10 + (v11 - v10) * fx;
  float v = top + (bot - top) * fy;
  upbf[(size_t)m * CCH + c] = f2bf(v);
  alignA[(size_t)m * 512 + 256 + c] = f2bf(2.f * v);
}

// ---------------------------------------------------------------------------
// Stage 3 (MFMA): fine_cal = (fine*scale) @ w_sel -> fp32 finecal (residual)
//                 + bf16 copy into alignA cols 0..255.  Tile 128x64, BK=64.
// XCD-clustered flat grid (A panel per-XCD L2 locality).
// ---------------------------------------------------------------------------
__global__ __launch_bounds__(256) void gemm_finecal_mfma(
    const float* __restrict__ fine, const float* __restrict__ scale,
    const unsigned short* __restrict__ w_selT,   // [256 n][256 k]
    float* __restrict__ finecal, unsigned short* __restrict__ alignA) {
  __shared__ unsigned short As[128][64];
  __shared__ unsigned short Bs[64][64];
  __shared__ float sc[256];
  int i = blockIdx.x;            // flat 0..511
  int xcd = i & 7, j = i >> 3;   // 16 mblk x 4 nblk per XCD
  int mblk = xcd * 16 + (j & 15);   // 0..127
  int nblk = j >> 4;                // 0..3
  int n0 = nblk * 64;
  int m0 = mblk * 128;
  int t = threadIdx.x;
  int wid = t >> 6, lane = t & 63;
  int lrow = lane & 15, lq = lane >> 4;
  int bb = m0 >> 12;  // 128 | 4096: no batch straddle
  sc[t] = scale[bb * 256 + t];
  f32x4 acc[2][4];
#pragma unroll
  for (int ii = 0; ii < 2; ++ii)
#pragma unroll
    for (int jj = 0; jj < 4; ++jj) acc[ii][jj] = (f32x4){0.f, 0.f, 0.f, 0.f};
  for (int k0 = 0; k0 < 256; k0 += 64) {
    __syncthreads();  // also covers sc[] on first iteration
    for (int u = t; u < 128 * 8; u += 256) {
      int row = u >> 3, ck = u & 7;
      const float* fp = &fine[(size_t)(m0 + row) * 256 + k0 + ck * 8];
      float4 f0 = *(const float4*)fp;
      float4 f1 = *(const float4*)(fp + 4);
      int kb = k0 + ck * 8;
      ushort4 u0 = make_ushort4(f2bf(f0.x * sc[kb]), f2bf(f0.y * sc[kb + 1]),
                                f2bf(f0.z * sc[kb + 2]), f2bf(f0.w * sc[kb + 3]));
      ushort4 u1 = make_ushort4(f2bf(f1.x * sc[kb + 4]), f2bf(f1.y * sc[kb + 5]),
                                f2bf(f1.z * sc[kb + 6]), f2bf(f1.w * sc[kb + 7]));
      int cb = (ck ^ (row & 7)) * 8;
      *(ushort4*)&As[row][cb] = u0;
      *(ushort4*)&As[row][cb + 4] = u1;
    }
    for (int u = t; u < 64 * 8; u += 256) {
      int row = u >> 3, ck = u & 7;
      *(uint4*)&Bs[row][(ck ^ (row & 7)) * 8] =
          *(const uint4*)&w_selT[(size_t)(n0 + row) * 256 + k0 + ck * 8];
    }
    __syncthreads();
#pragma unroll
    for (int kk = 0; kk < 2; ++kk) {
      int cs = ((kk * 4 + lq) ^ (lrow & 7)) * 8;
      bf16x8 a[2], b[4];
#pragma unroll
      for (int mt = 0; mt < 2; ++mt)
        a[mt] = *(const bf16x8*)&As[wid * 32 + mt * 16 + lrow][cs];
#pragma unroll
      for (int nt = 0; nt < 4; ++nt)
        b[nt] = *(const bf16x8*)&Bs[nt * 16 + lrow][cs];
#pragma unroll
      for (int mt = 0; mt < 2; ++mt)
#pragma unroll
        for (int nt = 0; nt < 4; ++nt)
          acc[mt][nt] = __builtin_amdgcn_mfma_f32_16x16x32_bf16(
              a[mt], b[nt], acc[mt][nt], 0, 0, 0);
    }
  }
#pragma unroll
  for (int mt = 0; mt < 2; ++mt)
#pragma unroll
    for (int nt = 0; nt < 4; ++nt)
#pragma unroll
      for (int r = 0; r < 4; ++r) {
        int m = m0 + wid * 32 + mt * 16 + lq * 4 + r;
        int n = n0 + nt * 16 + lrow;
        finecal[(size_t)m * 256 + n] = acc[mt][nt][r];
        alignA[(size_t)m * 512 + n] = f2bf(acc[mt][nt][r]);
      }
}

// ---------------------------------------------------------------------------
// Stage 4 (MFMA): align = alignA @ w_off -> bf16 [16384][512]
// gload_lds issue-early double-buffer + XCD-clustered flat grid.
// ---------------------------------------------------------------------------
__global__ __launch_bounds__(256) void gemm_align_mfma(
    const unsigned short* __restrict__ alignA,
    const unsigned short* __restrict__ w_offT,
    unsigned short* __restrict__ alignBf) {
  __shared__ unsigned short As[2][128][64];     // 32 KB
  __shared__ unsigned short Bs[2][64][64];      // 16 KB
  int i = blockIdx.x;            // flat 0..1023
  int xcd = i & 7, j = i >> 3;   // 16 mblk x 8 nblk per XCD
  int mblk = xcd * 16 + (j & 15);   // 0..127
  int nblk = j >> 4;                // 0..7
  int n0 = nblk * 64;
  int m0 = mblk * 128;
  int t = threadIdx.x;
  int wid = t >> 6, lane = t & 63;
  int lrow = lane & 15, lq = lane >> 4;
  f32x4 acc[2][4];
#pragma unroll
  for (int ii = 0; ii < 2; ++ii)
#pragma unroll
    for (int jj = 0; jj < 4; ++jj) acc[ii][jj] = (f32x4){0.f, 0.f, 0.f, 0.f};

  int lr8 = lane >> 3;          // row within 8-row group
  int lslot = lane & 7;         // physical 16B slot
  auto stageA = [&](int buf, int k0) {
#pragma unroll
    for (int ii = 0; ii < 4; ++ii) {
      int rg = wid * 4 + ii;            // 8-row group 0..15
      int row = rg * 8 + lr8;
      int ck = lslot ^ (row & 7);
      const unsigned short* src = &alignA[(size_t)(m0 + row) * 512 + k0 + ck * 8];
      __builtin_amdgcn_global_load_lds(
          (const __attribute__((address_space(1))) unsigned int*)src,
          (__attribute__((address_space(3))) unsigned int*)&As[buf][rg * 8][0],
          16, 0, 0);
    }
  };
  auto stageB = [&](int buf, int k0) {
#pragma unroll
    for (int ii = 0; ii < 2; ++ii) {
      int rg = wid * 2 + ii;            // 8-row group 0..7
      int row = rg * 8 + lr8;
      int ck = lslot ^ (row & 7);
      const unsigned short* src = &w_offT[(size_t)(n0 + row) * 512 + k0 + ck * 8];
      __builtin_amdgcn_global_load_lds(
          (const __attribute__((address_space(1))) unsigned int*)src,
          (__attribute__((address_space(3))) unsigned int*)&Bs[buf][rg * 8][0],
          16, 0, 0);
    }
  };

  stageA(0, 0);
  stageB(0, 0);
  __syncthreads();               // vmcnt(0) drain inserted by compiler
  int buf = 0;
  for (int kb = 0; kb < 8; ++kb) {
    if (kb + 1 < 8) {
      stageA(buf ^ 1, (kb + 1) * 64);  // async, flies under compute
      stageB(buf ^ 1, (kb + 1) * 64);
    }
#pragma unroll
    for (int kk = 0; kk < 2; ++kk) {
      int cs = ((kk * 4 + lq) ^ (lrow & 7)) * 8;
      bf16x8 a[2], b[4];
#pragma unroll
      for (int mt = 0; mt < 2; ++mt)
        a[mt] = *(const bf16x8*)&As[buf][wid * 32 + mt * 16 + lrow][cs];
#pragma unroll
      for (int nt = 0; nt < 4; ++nt)
        b[nt] = *(const bf16x8*)&Bs[buf][nt * 16 + lrow][cs];
#pragma unroll
      for (int mt = 0; mt < 2; ++mt)
#pragma unroll
        for (int nt = 0; nt < 4; ++nt)
          acc[mt][nt] = __builtin_amdgcn_mfma_f32_16x16x32_bf16(
              a[mt], b[nt], acc[mt][nt], 0, 0, 0);
    }
    __syncthreads();             // drains next-tile staging; all reads done
    buf ^= 1;
  }
#pragma unroll
  for (int mt = 0; mt < 2; ++mt)
#pragma unroll
    for (int nt = 0; nt < 4; ++nt)
#pragma unroll
      for (int r = 0; r < 4; ++r) {
        int m = m0 + wid * 32 + mt * 16 + lq * 4 + r;
        int n = n0 + nt * 16 + lrow;
        alignBf[(size_t)m * 512 + n] = f2bf(acc[mt][nt][r]);
      }
}

// ---------------------------------------------------------------------------
// Stage 5 (MFMA): om = conv3x3(align) + b_om  as 9 shifted GEMMs.
// R20: R13 tile (M=256 x N=64, 121.5 KB LDS, grid 256 = 1 block/CU) but
// 512 threads (8 waves = 2 waves/SIMD): wave = image row (wy) x 32-n half
// (wx); acc[4][2], 144 MFMA/c0/wave. Staging flattened across 8 waves
// (9 B-items + <=6 A-items each). Swizzles/barriers identical to R13.
// ---------------------------------------------------------------------------
__global__ __launch_bounds__(512) void om_conv_mfma(
    const unsigned short* __restrict__ alignBf,  // [16384][512] bf16
    const unsigned short* __restrict__ w_omT,    // [9][256 n][512 c] bf16
    const float* __restrict__ b_om,
    float* __restrict__ om) {                    // [16384][216] fp32
  __shared__ unsigned short As[6][66][64];      // 49.5 KB
  __shared__ unsigned short Bs[9][64][64];      // 72 KB
  int i = blockIdx.x;            // flat 0..255
  int xcd = i & 7, j = i >> 3;   // 32 blocks per XCD, contiguous m-band
  int mblk = xcd * 8 + (j >> 2);    // 0..63 (4 image rows each)
  int nblk = j & 3;                 // 0..3
  int b = mblk >> 4, hq = mblk & 15;
  int h0 = hq * 4;
  int n0 = nblk * 64;
  int t = threadIdx.x;           // 0..511
  int wid = t >> 6, lane = t & 63;  // 8 waves
  int wy = wid >> 1, wx = wid & 1;  // wave: image row h0+wy, n-half wx
  int lrow = lane & 15, lq = lane >> 4;
  const size_t imgbase = (size_t)b * 4096;
  f32x4 acc[4][2];
#pragma unroll
  for (int ii = 0; ii < 4; ++ii)
#pragma unroll
    for (int jj = 0; jj < 2; ++jj) acc[ii][jj] = (f32x4){0.f, 0.f, 0.f, 0.f};

  int lr8 = lane >> 3;   // sub-index within 8-row/8-px group
  int lslot = lane & 7;  // physical 16B slot

  // stage B: 72 items (9 taps x 8 row-groups), 9 per wave.
  auto stageB = [&](int c0) {
#pragma unroll
    for (int jj2 = 0; jj2 < 9; ++jj2) {
      int item = wid * 9 + jj2;         // 0..71
      int tap = item >> 3, rg = item & 7;
      int row = rg * 8 + lr8;
      int ck = lslot ^ lr8;             // row&7 == lr8
      const unsigned short* src =
          &w_omT[((size_t)tap * 256 + n0 + row) * 512 + c0 * 64 + ck * 8];
      __builtin_amdgcn_global_load_lds(
          (const __attribute__((address_space(1))) unsigned int*)src,
          (__attribute__((address_space(3))) unsigned int*)&Bs[tap][rg * 8][0],
          16, 0, 0);
    }
  };
  // stage A: 48 items (6 dy x 8 px-groups), 6 per wave.
  auto stageA = [&](int c0) {
#pragma unroll
    for (int jj2 = 0; jj2 < 6; ++jj2) {
      int item = wid * 6 + jj2;         // 0..47
      int dy = item >> 3, g = item & 7;
      int y = h0 - 1 + dy;
      if (y < 0 || y > 63) continue;    // OOB row stays pre-zeroed
      int px0 = 1 + g * 8;
      int px = px0 + lr8;
      int w = g * 8 + lr8;              // px - 1
      int ck = lslot ^ (px & 7);
      const unsigned short* src =
          &alignBf[(imgbase + (size_t)y * 64 + w) * 512 + c0 * 64 + ck * 8];
      __builtin_amdgcn_global_load_lds(
          (const __attribute__((address_space(1))) unsigned int*)src,
          (__attribute__((address_space(3))) unsigned int*)&As[dy][px0][0],
          16, 0, 0);
    }
  };

  // prologue: zero halo cols (px 0,65) for 6 rows, and fully-OOB dy rows.
  {
    uint4 z = make_uint4(0u, 0u, 0u, 0u);
    if (t < 96) {
      int dy = t >> 4;                    // 0..5
      int px = ((t >> 3) & 1) ? 65 : 0;
      int q = t & 7;
      *(uint4*)&As[dy][px][q * 8] = z;
    }
#pragma unroll
    for (int dy = 0; dy < 6; ++dy) {
      int y = h0 - 1 + dy;
      if (y < 0 || y > 63) {
        unsigned short* rowp = &As[dy][0][0];
        for (int u = t; u < 528; u += 512)  // 66*64 shorts = 528 uint4
          *(uint4*)&rowp[u * 8] = z;
      }
    }
  }
  stageA(0);
  stageB(0);

  for (int c0 = 0; c0 < 8; ++c0) {
    __syncthreads();  // drains staging (vmcnt) + zero writes
#pragma unroll
    for (int tap = 0; tap < 9; ++tap) {
      int dyt = tap / 3, dxt = tap - dyt * 3;
#pragma unroll
      for (int kk = 0; kk < 2; ++kk) {
        bf16x8 a[4], bb[2];
#pragma unroll
        for (int mt = 0; mt < 4; ++mt) {
          int prow = mt * 16 + lrow + dxt;
          a[mt] = *(const bf16x8*)&As[wy + dyt][prow][((kk * 4 + lq) ^ (prow & 7)) * 8];
        }
#pragma unroll
        for (int nt = 0; nt < 2; ++nt)
          bb[nt] = *(const bf16x8*)&Bs[tap][wx * 32 + nt * 16 + lrow]
                                      [((kk * 4 + lq) ^ (lrow & 7)) * 8];
#pragma unroll
        for (int mt = 0; mt < 4; ++mt)
#pragma unroll
          for (int nt = 0; nt < 2; ++nt)
            acc[mt][nt] = __builtin_amdgcn_mfma_f32_16x16x32_bf16(
                a[mt], bb[nt], acc[mt][nt], 0, 0, 0);
      }
    }
    __syncthreads();  // all reads done before restage
    if (c0 < 7) {
      stageA(c0 + 1);
      stageB(c0 + 1);
    }
  }
  // epilogue: direct store + bias (n < 216)
#pragma unroll
  for (int nt = 0; nt < 2; ++nt) {
    int n = n0 + wx * 32 + nt * 16 + lrow;
    if (n < OMC) {
      float bias = b_om[n];
#pragma unroll
      for (int mt = 0; mt < 4; ++mt) {
#pragma unroll
        for (int r = 0; r < 4; ++r) {
          size_t m = imgbase + (size_t)(h0 + wy) * 64 + mt * 16 + lq * 4 + r;
          om[m * OMC + n] = acc[mt][nt][r] + bias;
        }
      }
    }
  }
}

// ---------------------------------------------------------------------------
// Stage 6 (FUSED): deformable sampling + out = relu(S @ w_dcnT + b_dcn) + finecal
// R19 (proven 58 us): 1024 threads (16 waves = 4 waves/SIMD), 112 KB LDS,
// 1 block/CU, grid 256. Waves 0-7 sample + computeOW; waves 8-15 stage B.
// GEMM: wave = m-half x f-slice (acc[2][2]).
// ---------------------------------------------------------------------------
__global__ __launch_bounds__(1024) void dcn_fused(
    const float* __restrict__ om, const unsigned short* __restrict__ upbf,
    const unsigned short* __restrict__ w_dcnT,  // [9][256 f][256 c]
    const float* __restrict__ b_dcn,
    const float* __restrict__ finecal,
    float* __restrict__ outp) {
  __shared__ unsigned short As[2][64][64];    // 16 KB
  __shared__ unsigned short Bs[2][256][64];   // 64 KB
  __shared__ int   offs[2][64][8][4];         // 16 KB
  __shared__ float wts[2][64][8][4];          // 16 KB
  int i = blockIdx.x;            // 0..255
  int xcd = i & 7, j = i >> 3;   // contiguous 32-row band per XCD
  int bh = xcd * 32 + j;         // 0..255 (b*64+h)
  int b = bh >> 6, h = bh & 63;
  const size_t m0 = (size_t)bh * 64;
  const unsigned short* upb = upbf + (size_t)b * HWP * CCH;
  int t = threadIdx.x;           // 0..1023
  int wid = t >> 6, lane = t & 63;   // 16 waves
  int lrow = lane & 15, lq = lane >> 4;
  int mh = wid >> 3;             // m-half 0..1 (rows mh*32..)
  int fi = wid & 7;              // f-slice 0..7 (f = fi*32..)
  bool sampler = (wid < 8);      // waves 0-7 sample; 8-15 stage B
  f32x4 acc[2][2];
#pragma unroll
  for (int ii = 0; ii < 2; ++ii)
#pragma unroll
    for (int jj = 0; jj < 2; ++jj) acc[ii][jj] = (f32x4){0.f, 0.f, 0.f, 0.f};

  int lr8 = lane >> 3;   // row within 8-row group
  int lslot = lane & 7;  // physical 16B slot
  int px_s = (t & 511) >> 3, sub_s = t & 7;  // sampling decomposition (t<512)

  // named gather registers (T14 in-flight state): 4 per sampler thread
  uint4 g0, g1, g2, g3;
  float4 wv;

  // per-tap offsets/weights for all 64 px x 8 groups (512 entries; t<512)
  auto computeOW = [&](int owb, int tap) {
    if (t >= 512) return;              // wave-uniform (waves 0-7 only)
    int ky = tap / 3, kx = tap - ky * 3;
    int e = t;
    {
      int p = e >> 3, gg = e & 7;
      const float* omr = om + (m0 + p) * OMC;
      float dy = omr[gg * 18 + tap * 2];
      float dx = omr[gg * 18 + tap * 2 + 1];
      float mk = 1.0f / (1.0f + expf(-omr[144 + gg * 9 + tap]));
      float sy = (float)(h + ky - 1) + dy;
      float sx = (float)(p + kx - 1) + dx;
      float y0f = floorf(sy), x0f = floorf(sx);
      float fy = sy - y0f, fx = sx - x0f;
      int y0 = (int)y0f, x0 = (int)x0f;
      int y1 = y0 + 1, x1 = x0 + 1;
      float vy0 = (y0 >= 0 && y0 <= 63) ? 1.f : 0.f;
      float vy1 = (y1 >= 0 && y1 <= 63) ? 1.f : 0.f;
      float vx0 = (x0 >= 0 && x0 <= 63) ? 1.f : 0.f;
      float vx1 = (x1 >= 0 && x1 <= 63) ? 1.f : 0.f;
      int yc0 = min(max(y0, 0), 63), yc1 = min(max(y1, 0), 63);
      int xc0 = min(max(x0, 0), 63), xc1 = min(max(x1, 0), 63);
      offs[owb][p][gg][0] = (yc0 * 64 + xc0) * 256;
      offs[owb][p][gg][1] = (yc0 * 64 + xc1) * 256;
      offs[owb][p][gg][2] = (yc1 * 64 + xc0) * 256;
      offs[owb][p][gg][3] = (yc1 * 64 + xc1) * 256;
      wts[owb][p][gg][0] = (1.f - fy) * (1.f - fx) * vy0 * vx0 * mk;
      wts[owb][p][gg][1] = (1.f - fy) * fx * vy0 * vx1 * mk;
      wts[owb][p][gg][2] = fy * (1.f - fx) * vy1 * vx0 * mk;
      wts[owb][p][gg][3] = fy * fx * vy1 * vx1 * mk;
    }
  };

  // stage B[256 f][64 c] for kb via global_load_lds (waves 8-15; 32 loads)
  auto stageB = [&](int buf, int kb) {
    if (wid < 8) return;               // wave-uniform
    int tap = kb >> 2, c0 = (kb & 3) * 64;
    int w8 = wid - 8;
#pragma unroll
    for (int ii = 0; ii < 4; ++ii) {
      int rg = w8 * 4 + ii;             // 8-row group 0..31
      int row = rg * 8 + lr8;
      int ck = lslot ^ (row & 7);
      const unsigned short* src =
          &w_dcnT[((size_t)tap * 256 + row) * 256 + c0 + ck * 8];
      __builtin_amdgcn_global_load_lds(
          (const __attribute__((address_space(1))) unsigned int*)src,
          (__attribute__((address_space(3))) unsigned int*)&Bs[buf][rg * 8][0],
          16, 0, 0);
    }
  };

  // T14 part 1: issue the 4 corner gathers into named registers (waves 0-7).
  auto sampleLoad = [&](int kb, int owb) {
    if (!sampler) return;
    int c0q = kb & 3;
    int g = c0q * 2 + (sub_s >> 2);     // DCN group = channel>>5
    int4 o = *(const int4*)&offs[owb][px_s][g][0];
    wv = *(const float4*)&wts[owb][px_s][g][0];
    int c = c0q * 64 + (sub_s >> 2) * 32 + (sub_s & 3) * 8;
    g0 = *(const uint4*)&upb[o.x + c];
    g1 = *(const uint4*)&upb[o.y + c];
    g2 = *(const uint4*)&upb[o.z + c];
    g3 = *(const uint4*)&upb[o.w + c];
  };
  // T14 part 2: blend + swizzled ds_write (runs after the MFMA cluster).
  auto sampleStore = [&](int buf) {
    if (!sampler) return;
    uint4 res;
    res.x = blend1(g0.x, g1.x, g2.x, g3.x, wv);
    res.y = blend1(g0.y, g1.y, g2.y, g3.y, wv);
    res.z = blend1(g0.z, g1.z, g2.z, g3.z, wv);
    res.w = blend1(g0.w, g1.w, g2.w, g3.w, wv);
    *(uint4*)&As[buf][px_s][(sub_s ^ (px_s & 7)) * 8] = res;
  };

  auto gemmStep = [&](int buf) {
#pragma unroll
    for (int kk = 0; kk < 2; ++kk) {
      int cs = ((kk * 4 + lq) ^ (lrow & 7)) * 8;
      bf16x8 a[2], bv[2];
#pragma unroll
      for (int mt = 0; mt < 2; ++mt)
        a[mt] = *(const bf16x8*)&As[buf][mh * 32 + mt * 16 + lrow][cs];
#pragma unroll
      for (int nt = 0; nt < 2; ++nt)
        bv[nt] = *(const bf16x8*)&Bs[buf][fi * 32 + nt * 16 + lrow][cs];
#pragma unroll
      for (int mt = 0; mt < 2; ++mt)
#pragma unroll
        for (int nt = 0; nt < 2; ++nt)
          acc[mt][nt] = __builtin_amdgcn_mfma_f32_16x16x32_bf16(
              a[mt], bv[nt], acc[mt][nt], 0, 0, 0);
    }
  };

  // prologue: ow(0), then stage tile 0 (load + immediate store)
  computeOW(0, 0);
  __syncthreads();              // ow(0) visible
  sampleLoad(0, 0);
  stageB(0, 0);
  sampleStore(0);

  int buf = 0;
  for (int kb = 0; kb < 36; ++kb) {
    int tap = kb >> 2, c0q = kb & 3;
    __syncthreads();            // drains sample writes + stage vmcnt; prior
                                // reads of buf^1 finished -> safe to rewrite
    int nkb = kb + 1;
    if (nkb < 36) {
      sampleLoad(nkb, (nkb >> 2) & 1);  // gathers in flight
      stageB(buf ^ 1, nkb);             // async, under compute
    }
    gemmStep(buf);              // MFMA cluster covers gather latency
    if (c0q == 2 && tap < 8) computeOW((tap + 1) & 1, tap + 1);
    if (nkb < 36) sampleStore(buf ^ 1);
    buf ^= 1;
  }

  // epilogue: out = relu(acc + bias) + finecal
#pragma unroll
  for (int mt = 0; mt < 2; ++mt)
#pragma unroll
    for (int nt = 0; nt < 2; ++nt) {
      int f = fi * 32 + nt * 16 + lrow;
      float bias = b_dcn[f];
#pragma unroll
      for (int r = 0; r < 4; ++r) {
        size_t m = m0 + mh * 32 + mt * 16 + lq * 4 + r;
        float v = fmaxf(acc[mt][nt][r] + bias, 0.f);
        float fc = __builtin_nontemporal_load(&finecal[m * 256 + f]);
        __builtin_nontemporal_store(v + fc, &outp[m * 256 + f]);
      }
    }
}

// ---------------------------------------------------------------------------
extern "C" void kernel_launch(void* const* d_in, const int* in_sizes, int n_in,
                              void* d_out, int out_size, void* d_ws, size_t ws_size,
                              hipStream_t stream) {
  const float* coarse = (const float*)d_in[0];
  const float* fine   = (const float*)d_in[1];
  const float* w_att  = (const float*)d_in[2];
  const float* w_sel  = (const float*)d_in[3];
  const float* w_off  = (const float*)d_in[4];
  const float* w_om   = (const float*)d_in[5];
  const float* b_om   = (const float*)d_in[6];
  const float* w_dcn  = (const float*)d_in[7];
  const float* b_dcn  = (const float*)d_in[8];
  float* outp = (float*)d_out;

  char* base = (char*)d_ws;
  size_t o = 0;
  float* scale            = (float*)(base + o);          o += 4096;
  float* finecal          = (float*)(base + o);          o += 16777216;
  float* omb              = (float*)(base + o);          o += 14155776;
  unsigned short* upbf    = (unsigned short*)(base + o); o += 8388608;
  unsigned short* w_offT  = (unsigned short*)(base + o); o += 524288;
  unsigned short* w_omT   = (unsigned short*)(base + o); o += 2359296;  // 9*256*512
  unsigned short* w_selT  = (unsigned short*)(base + o); o += 131072;
  unsigned short* w_dcnT  = (unsigned short*)(base + o); o += 1179648;
  unsigned short* scratch = (unsigned short*)(base + o);  // align region
  // alignA/alignBf live in the former S region (dead by dcn time):
  unsigned short* alignA  = scratch;
  unsigned short* alignBf = (unsigned short*)((char*)scratch + 16777216);
  // partial pooling buffer aliases omb (dead until om_conv writes it)
  float* partial = omb;

  prep_transpose<<<dim3(2048), dim3(256), 0, stream>>>(
      w_off, w_om, w_sel, w_dcn, w_offT, w_omT, w_selT, w_dcnT);
  pool_partial<<<dim3(64, 4), dim3(256), 0, stream>>>(fine, partial);
  pool_finish<<<dim3(4), dim3(256), 0, stream>>>(partial, w_att, scale);
  upsample_kernel<<<dim3(16384), dim3(256), 0, stream>>>(coarse, upbf, alignA);
  gemm_finecal_mfma<<<dim3(512), dim3(256), 0, stream>>>(
      fine, scale, w_selT, finecal, alignA);
  gemm_align_mfma<<<dim3(1024), dim3(256), 0, stream>>>(alignA, w_offT, alignBf);
  om_conv_mfma<<<dim3(256), dim3(512), 0, stream>>>(alignBf, w_omT, b_om, omb);
  dcn_fused<<<dim3(256), dim3(1024), 0, stream>>>(
      omb, upbf, w_dcnT, b_dcn, finecal, outp);
}